// Round 6
// baseline (1119.970 us; speedup 1.0000x reference)
//
#include <hip/hip_runtime.h>
#include <math.h>

// Problem constants
#define T_   8
#define K_   64
#define D_   512
#define CIN_ 1536
#define B_   32
#define S_   64    // H*W = 8*8
#define NT_  256   // B*T

// Workspace layout (float offsets)
#define WLO_BF16  786432u     // bf16-element offset of Wlo within bf16 view
#define WXT_OFF   786432u     // [512][64]  transposed w_x (float offset)
#define XT_OFF    819200u     // [256][512][64]
#define WXPB_OFF  9207808u    // [256][64][64]
#define ATTV_OFF  10256384u   // [256][64][64]  (n = b*8+t)
#define HS_OFF    11436032u   // [8][32][64][64]
#define ASUM_OFF  13041664u   // [32][8][64]
// conv-weight pack (bf16 elements): 5 weights x (hi 36864 + lo 36864),
// layout per weight: [dydx(9)][o(64)][i(64)]. Since R4 only hi halves are read.
#define WPB       25034752u

typedef __bf16 v8bf __attribute__((ext_vector_type(8)));
typedef __bf16 v4bf __attribute__((ext_vector_type(4)));
typedef float  v4f  __attribute__((ext_vector_type(4)));
typedef _Float16 v4h __attribute__((ext_vector_type(4)));
typedef _Float16 v8h __attribute__((ext_vector_type(8)));

// ---------------------------------------------------------------------------
// prep: split redu_w -> bf16 hi/lo, transpose w_x -> wxT[d][k]
__global__ __launch_bounds__(256) void k_prep(const float* __restrict__ redu_w,
                                              const float* __restrict__ w_x,
                                              float* __restrict__ ws) {
    unsigned idx = blockIdx.x * 256u + threadIdx.x;
    if (idx < 786432u) {
        float f = redu_w[idx];
        __bf16 h = (__bf16)f;
        __bf16 l = (__bf16)(f - (float)h);
        __bf16* wb = (__bf16*)ws;
        wb[idx] = h;
        wb[WLO_BF16 + idx] = l;
    } else if (idx < 819200u) {
        unsigned i = idx - 786432u;
        unsigned dd = i >> 6, k = i & 63u;
        ws[WXT_OFF + i] = w_x[k * 512u + dd];
    }
}

// ---------------------------------------------------------------------------
// prep conv weights: [o][i][ky][kx] fp32 -> bf16 hi/lo [dydx][o][i]
__global__ __launch_bounds__(256) void k_prep_w(const float* __restrict__ w0,
                                                const float* __restrict__ w1,
                                                const float* __restrict__ w2,
                                                const float* __restrict__ w3,
                                                const float* __restrict__ w4,
                                                float* __restrict__ ws) {
    unsigned idx = blockIdx.x * 256u + threadIdx.x;
    if (idx >= 184320u) return;
    unsigned w = idx / 36864u, r = idx % 36864u;
    const float* src = (w == 0) ? w0 : (w == 1) ? w1 : (w == 2) ? w2 : (w == 3) ? w3 : w4;
    float f = src[r];
    __bf16 h = (__bf16)f;
    __bf16 l = (__bf16)(f - (float)h);
    unsigned o = r / 576u, rem = r % 576u, ii = rem / 9u, dydx = rem % 9u;
    __bf16* wb = (__bf16*)ws;
    unsigned dst = WPB + w * 73728u + (dydx * 64u + o) * 64u + ii;
    wb[dst] = h;
    wb[dst + 36864u] = l;
}

// ---------------------------------------------------------------------------
// xt = redu_w @ x + redu_b via bf16 hi/lo split MFMA (3 products).
__global__ __launch_bounds__(256) void k_gemm_xt_mfma(const float* __restrict__ x,
                                                      const float* __restrict__ redu_b,
                                                      float* __restrict__ ws) {
    __shared__ __bf16 xhi_s[64 * 72];
    __shared__ __bf16 xlo_s[64 * 72];
    const __bf16* __restrict__ Whi = (const __bf16*)ws;
    const __bf16* __restrict__ Wlo = ((const __bf16*)ws) + WLO_BF16;
    float* xt = ws + XT_OFF;
    const int n = blockIdx.y;
    const int d0 = blockIdx.x * 256;
    const int tid = threadIdx.x;
    const int wave = tid >> 6, lane = tid & 63;
    const int lrow = lane & 15, lkg = lane >> 4;
    const int m_base = d0 + wave * 64;
    const float* __restrict__ xn = x + n * 98304;
    const int s4 = tid & 15, cb = tid >> 4;

    v4f acc[4][4];
#pragma unroll
    for (int mt = 0; mt < 4; ++mt)
#pragma unroll
        for (int nt = 0; nt < 4; ++nt) acc[mt][nt] = (v4f){0.f, 0.f, 0.f, 0.f};

    for (int c0 = 0; c0 < 1536; c0 += 64) {
        float4 v[4];
#pragma unroll
        for (int j = 0; j < 4; ++j)
            v[j] = *(const float4*)&xn[(c0 + cb * 4 + j) * 64 + s4 * 4];
        __syncthreads();
#pragma unroll
        for (int i = 0; i < 4; ++i) {
            v4bf hv, lv;
#pragma unroll
            for (int j = 0; j < 4; ++j) {
                float f = ((const float*)&v[j])[i];
                __bf16 h = (__bf16)f;
                hv[j] = h;
                lv[j] = (__bf16)(f - (float)h);
            }
            int row = s4 * 4 + i;
            *(v4bf*)&xhi_s[row * 72 + cb * 4] = hv;
            *(v4bf*)&xlo_s[row * 72 + cb * 4] = lv;
        }
        __syncthreads();
#pragma unroll
        for (int ks = 0; ks < 64; ks += 32) {
            v8bf bh[4], bl[4], ah[4], al[4];
#pragma unroll
            for (int nt = 0; nt < 4; ++nt) {
                int off = (nt * 16 + lrow) * 72 + ks + lkg * 8;
                bh[nt] = *(const v8bf*)&xhi_s[off];
                bl[nt] = *(const v8bf*)&xlo_s[off];
            }
#pragma unroll
            for (int mt = 0; mt < 4; ++mt) {
                int gi = (m_base + mt * 16 + lrow) * 1536 + c0 + ks + lkg * 8;
                ah[mt] = *(const v8bf*)&Whi[gi];
                al[mt] = *(const v8bf*)&Wlo[gi];
            }
#pragma unroll
            for (int mt = 0; mt < 4; ++mt)
#pragma unroll
                for (int nt = 0; nt < 4; ++nt) {
                    acc[mt][nt] = __builtin_amdgcn_mfma_f32_16x16x32_bf16(
                        ah[mt], bh[nt], acc[mt][nt], 0, 0, 0);
                    acc[mt][nt] = __builtin_amdgcn_mfma_f32_16x16x32_bf16(
                        ah[mt], bl[nt], acc[mt][nt], 0, 0, 0);
                    acc[mt][nt] = __builtin_amdgcn_mfma_f32_16x16x32_bf16(
                        al[mt], bh[nt], acc[mt][nt], 0, 0, 0);
                }
        }
    }
#pragma unroll
    for (int mt = 0; mt < 4; ++mt) {
#pragma unroll
        for (int r = 0; r < 4; ++r) {
            int m = m_base + mt * 16 + lkg * 4 + r;
            float bias = redu_b[m];
#pragma unroll
            for (int nt = 0; nt < 4; ++nt) {
                int s = nt * 16 + lrow;
                xt[(n * 512 + m) * 64 + s] = acc[mt][nt][r] + bias;
            }
        }
    }
}

// ---------------------------------------------------------------------------
// wxpb = w_x @ xt ; per n: (64x512)@(512x64). grid 256, block 256, 4x4/thread.
__global__ __launch_bounds__(256) void k_gemm_wxpb(float* __restrict__ ws) {
    __shared__ float Aw[16 * 64];
    __shared__ float Bx[16 * 64];
    const float* wxT = ws + WXT_OFF;
    const float* xt = ws + XT_OFF;
    float* wxpb = ws + WXPB_OFF;
    const int n = blockIdx.x;
    const int tid = threadIdx.x;
    const int sg = tid & 15, kg = tid >> 4;

    float acc[4][4];
#pragma unroll
    for (int i = 0; i < 4; ++i)
#pragma unroll
        for (int j = 0; j < 4; ++j) acc[i][j] = 0.f;

    for (int d0 = 0; d0 < 512; d0 += 16) {
        int cc = tid >> 4, q = tid & 15;
        *(float4*)&Aw[cc * 64 + q * 4] = *(const float4*)&wxT[(d0 + cc) * 64 + q * 4];
        *(float4*)&Bx[cc * 64 + q * 4] = *(const float4*)&xt[n * 32768 + (d0 + cc) * 64 + q * 4];
        __syncthreads();
#pragma unroll
        for (int c2 = 0; c2 < 16; ++c2) {
            float4 a = *(const float4*)&Aw[c2 * 64 + kg * 4];
            float4 b = *(const float4*)&Bx[c2 * 64 + sg * 4];
            float av[4] = {a.x, a.y, a.z, a.w};
            float bv[4] = {b.x, b.y, b.z, b.w};
#pragma unroll
            for (int i = 0; i < 4; ++i)
#pragma unroll
                for (int j = 0; j < 4; ++j)
                    acc[i][j] = fmaf(av[i], bv[j], acc[i][j]);
        }
        __syncthreads();
    }
#pragma unroll
    for (int i = 0; i < 4; ++i) {
        float4 o = {acc[i][0], acc[i][1], acc[i][2], acc[i][3]};
        *(float4*)&wxpb[(n * 64 + kg * 4 + i) * 64 + sg * 4] = o;
    }
}

// ---------------------------------------------------------------------------
// generic 3x3 conv (fp32), used only for attv (256 parallel images).
__global__ __launch_bounds__(128) void k_conv3x3(const float* __restrict__ in,
                                                 const float* __restrict__ wt,
                                                 const float* __restrict__ bias,
                                                 float* __restrict__ out) {
    __shared__ float in_s[4096];
    __shared__ float w_s[16 * 576];
    const int img = blockIdx.y;
    const int k0 = blockIdx.x * 16;
    const int tid = threadIdx.x;
    const int kl = tid >> 3, y = tid & 7;
#pragma unroll
    for (int i = 0; i < 8; ++i) {
        int f = tid + i * 128;
        *(float4*)&in_s[f * 4] = *(const float4*)&in[img * 4096 + f * 4];
    }
#pragma unroll
    for (int i = 0; i < 18; ++i) {
        int f = tid + i * 128;
        *(float4*)&w_s[f * 4] = *(const float4*)&wt[k0 * 576 + f * 4];
    }
    __syncthreads();
    float o[8];
#pragma unroll
    for (int xx = 0; xx < 8; ++xx) o[xx] = 0.f;
    for (int kp = 0; kp < 64; ++kp) {
        const float* wp = &w_s[kl * 576 + kp * 9];
        float wv[9];
#pragma unroll
        for (int q = 0; q < 9; ++q) wv[q] = wp[q];
#pragma unroll
        for (int dy = 0; dy < 3; ++dy) {
            int yy = y + dy - 1;
            if (yy >= 0 && yy < 8) {
                float4 ra = *(const float4*)&in_s[kp * 64 + yy * 8];
                float4 rb = *(const float4*)&in_s[kp * 64 + yy * 8 + 4];
                float r[8] = {ra.x, ra.y, ra.z, ra.w, rb.x, rb.y, rb.z, rb.w};
                float wa = wv[dy * 3 + 0], wb = wv[dy * 3 + 1], wc = wv[dy * 3 + 2];
#pragma unroll
                for (int xx = 0; xx < 8; ++xx) {
                    float t = wb * r[xx];
                    if (xx > 0) t += wa * r[xx - 1];
                    if (xx < 7) t += wc * r[xx + 1];
                    o[xx] += t;
                }
            }
        }
    }
    float bv = bias ? bias[k0 + kl] : 0.f;
    float4 o0 = {o[0] + bv, o[1] + bv, o[2] + bv, o[3] + bv};
    float4 o1 = {o[4] + bv, o[5] + bv, o[6] + bv, o[7] + bv};
    *(float4*)&out[img * 4096 + (k0 + kl) * 64 + y * 8] = o0;
    *(float4*)&out[img * 4096 + (k0 + kl) * 64 + y * 8 + 4] = o1;
}

// ---------------------------------------------------------------------------
// 3x3 conv as 9 shifted MFMA GEMMs, 16-wave version (R6): each wave owns one
// 16-col output group (mt = wave>>2 rows, nq = wave&3 cols), single v4f acc.
// Per-wave chain halves vs the 8-wave version; weight loads keep R4's proven
// per-dy 6-fragment batch (R5 showed bigger batches spill under the 128 cap).
__device__ __forceinline__ v4f conv_mfma(const __bf16* __restrict__ Wh,
                                         const __bf16* tS,
                                         int l15, int kg8, int mt, int nq) {
    v8bf vz;
#pragma unroll
    for (int q = 0; q < 8; ++q) vz[q] = (__bf16)0.f;
    v4f a = (v4f){0.f, 0.f, 0.f, 0.f};
    const int n0 = nq * 16 + l15;
    const int y = n0 >> 3, x = n0 & 7;
#pragma unroll
    for (int dy = 0; dy < 3; ++dy) {
        // batch-load this dy-row's 6 weight fragments (3 taps x 2 kc)
        v8bf wh[3][2];
#pragma unroll
        for (int dx = 0; dx < 3; ++dx) {
            const int wrow = ((dy * 3 + dx) * 64 + mt * 16 + l15) * 64 + kg8;
#pragma unroll
            for (int kci = 0; kci < 2; ++kci)
                wh[dx][kci] = *(const v8bf*)&Wh[wrow + kci * 32];
        }
#pragma unroll
        for (int dx = 0; dx < 3; ++dx) {
            const int y0 = y + dy - 1, x0 = x + dx - 1;
            const bool ok = ((unsigned)y0 < 8u) & ((unsigned)x0 < 8u);
            const int s0 = ((y0 * 8 + x0) & 63) * 72 + kg8;
#pragma unroll
            for (int kci = 0; kci < 2; ++kci) {
                v8bf b0 = ok ? *(const v8bf*)&tS[s0 + kci * 32] : vz;
                a = __builtin_amdgcn_mfma_f32_16x16x32_bf16(wh[dx][kci], b0, a, 0, 0, 0);
            }
        }
    }
    return a;
}

// ---------------------------------------------------------------------------
// Whole recurrence in one kernel: grid 32 (one block per b), 1024 threads.
// h lives in LDS across all 8 steps; convs on MFMA.
// R6: 16 waves (4/SIMD, double the latency hiding; per-wave conv work halves).
// wxv reg-hoist dropped (frees 64 VGPRs -> live set well under the 128 cap,
// which R4<->R5 evidence shows is what kills the residual spill traffic);
// wxtp reads wxpb from global (L2-resident, 16 independent loads).
// Occupancy attributes removed: all three forms proved inert (R2/R3/R5).
__global__ __launch_bounds__(1024) void k_recur(const float* __restrict__ att_b,
                                                const float* __restrict__ share_b,
                                                const float* __restrict__ fc1_w,
                                                const float* __restrict__ fc2_w,
                                                float* __restrict__ ws) {
    __shared__ float h_s[4096];                                   // h [k][s]
    __shared__ __attribute__((aligned(16))) __bf16 tA[64 * 72];   // T(in) [s][kp]
    __shared__ float cA[64 * 65];                                 // conv out / scratch
    __shared__ float cB[64 * 65];
    __shared__ float misc[1088];  // em|exs [0..511], ex|als [512..1023], h1|asum [1024..]
    __shared__ __attribute__((aligned(16))) _Float16 attv_s[32768];  // [tp][k][s] fp16
    const int b = blockIdx.x, tid = threadIdx.x;
    const int lane = tid & 63;
    const int wave = tid >> 6, mt = wave >> 2, nq = wave & 3;
    const int l15 = lane & 15, kg = lane >> 4, kg8 = kg * 8;
    const int kk2 = (tid >> 3) & 63, yy = tid & 7, half = tid >> 9;
    const __bf16* Wp = (const __bf16*)ws + WPB;
    const float* attv = ws + ATTV_OFF;
    const float* wxpb = ws + WXPB_OFF;
    float* hsg = ws + HS_OFF;
    float* asg = ws + ASUM_OFF;

    // ---- one-time: stage attv (this b) into LDS as fp16
    {
        const float* src = attv + b * 32768;
        for (int i = tid; i < 8192; i += 1024) {
            float4 v = *(const float4*)&src[i * 4];
            v4h h4 = {(_Float16)v.x, (_Float16)v.y, (_Float16)v.z, (_Float16)v.w};
            *(v4h*)&attv_s[i * 4] = h4;
        }
    }

    for (int i = tid; i < 4096; i += 1024) h_s[i] = 0.f;
    const float abv = att_b[kk2];
    float sb4[4];
#pragma unroll
    for (int r = 0; r < 4; ++r) sb4[r] = share_b[mt * 16 + kg * 4 + r];
    __syncthreads();

    for (int t = 0; t < 8; ++t) {
        // ---- tA = T(h): 16 groups x 4 rows
        {
            int s = tid & 63, g = tid >> 6;
            v4bf hv;
#pragma unroll
            for (int q = 0; q < 4; ++q) hv[q] = (__bf16)h_s[(g * 4 + q) * 64 + s];
            *(v4bf*)&tA[s * 72 + g * 4] = hv;
        }
        __syncthreads();
        // ---- ah conv -> cA
        {
            v4f a = conv_mfma(Wp, tA, l15, kg8, mt, nq);
#pragma unroll
            for (int r = 0; r < 4; ++r)
                cA[(mt * 16 + kg * 4 + r) * 65 + nq * 16 + l15] = a[r];
        }
        __syncthreads();
        // ---- e = relu(attv+ah); mean/max over s -> em/ex (1024 thr, 4 tp each)
        {
            float ah8[8];
            const float* cr = &cA[kk2 * 65 + yy * 8];
#pragma unroll
            for (int xx = 0; xx < 8; ++xx) ah8[xx] = cr[xx] + abv;
#pragma unroll
            for (int tp = 0; tp < 4; ++tp) {
                int tpa = half * 4 + tp;
                v8h va = *(const v8h*)&attv_s[tpa * 4096 + kk2 * 64 + yy * 8];
                float s_ = 0.f, m_ = 0.f;
#pragma unroll
                for (int xx = 0; xx < 8; ++xx) {
                    float v = fmaxf((float)va[xx] + ah8[xx], 0.f);
                    s_ += v;
                    m_ = fmaxf(m_, v);
                }
                s_ += __shfl_down(s_, 4, 8);
                s_ += __shfl_down(s_, 2, 8);
                s_ += __shfl_down(s_, 1, 8);
                m_ = fmaxf(m_, __shfl_down(m_, 4, 8));
                m_ = fmaxf(m_, __shfl_down(m_, 2, 8));
                m_ = fmaxf(m_, __shfl_down(m_, 1, 8));
                if (yy == 0) {
                    misc[tpa * 64 + kk2] = s_ * (1.f / 64.f);
                    misc[512 + tpa * 64 + kk2] = m_;
                }
            }
        }
        __syncthreads();
        // ---- fc1: 64 outputs x 16 partials (1024 thr)
        {
            int i2 = tid >> 4, part = tid & 15;
            int i = i2 & 31;
            const float* src = misc + ((i2 < 32) ? 0 : 512);
            const float* wrow = fc1_w + i * 512 + part * 32;
            const float* s2 = src + part * 32;
            float p = 0.f;
#pragma unroll
            for (int c4 = 0; c4 < 8; ++c4) {
                float4 wv = *(const float4*)&wrow[c4 * 4];
                float4 sv = *(const float4*)&s2[c4 * 4];
                p = fmaf(wv.x, sv.x, p);
                p = fmaf(wv.y, sv.y, p);
                p = fmaf(wv.z, sv.z, p);
                p = fmaf(wv.w, sv.w, p);
            }
            p += __shfl_down(p, 8, 16);
            p += __shfl_down(p, 4, 16);
            p += __shfl_down(p, 2, 16);
            p += __shfl_down(p, 1, 16);
            if (part == 0) misc[1024 + i2] = fmaxf(p, 0.f);
        }
        __syncthreads();
        // ---- fc2 + tanh + exp -> exs at misc[0..511] (tid<512)
        if (tid < 512) {
            const float* w2 = fc2_w + tid * 32;
            float gm = 0.f, gx = 0.f;
#pragma unroll
            for (int i4 = 0; i4 < 8; ++i4) {
                float4 wv = *(const float4*)&w2[i4 * 4];
                gm = fmaf(wv.x, misc[1024 + i4 * 4 + 0], gm);
                gm = fmaf(wv.y, misc[1024 + i4 * 4 + 1], gm);
                gm = fmaf(wv.z, misc[1024 + i4 * 4 + 2], gm);
                gm = fmaf(wv.w, misc[1024 + i4 * 4 + 3], gm);
                gx = fmaf(wv.x, misc[1056 + i4 * 4 + 0], gx);
                gx = fmaf(wv.y, misc[1056 + i4 * 4 + 1], gx);
                gx = fmaf(wv.z, misc[1056 + i4 * 4 + 2], gx);
                gx = fmaf(wv.w, misc[1056 + i4 * 4 + 3], gx);
            }
            misc[tid] = expf(tanhf(gm + gx));
        }
        __syncthreads();
        // ---- softmax over T -> als at misc[512..1023] (tid<512)
        if (tid < 512) {
            int k6 = tid & 63;
            float den = 0.f;
#pragma unroll
            for (int tp = 0; tp < 8; ++tp) den += misc[tp * 64 + k6];
            den += (den == 0.f) ? 1.f : 0.f;
            misc[512 + tid] = misc[tid] / den;
        }
        __syncthreads();
        // ---- wxtp: read wxpb from global (L2-resident), weighted by als (tid<512)
        float wx8[8];
        if (tid < 512) {
#pragma unroll
            for (int xx = 0; xx < 8; ++xx) wx8[xx] = 0.f;
            const float* src0 = wxpb + b * 32768 + kk2 * 64 + yy * 8;
#pragma unroll
            for (int tp = 0; tp < 8; ++tp) {
                float al = misc[512 + tp * 64 + kk2];
                float4 v0 = *(const float4*)&src0[tp * 4096];
                float4 v1 = *(const float4*)&src0[tp * 4096 + 4];
                float v[8] = {v0.x, v0.y, v0.z, v0.w, v1.x, v1.y, v1.z, v1.w};
#pragma unroll
                for (int xx = 0; xx < 8; ++xx) wx8[xx] = fmaf(al, v[xx], wx8[xx]);
            }
        }
        // ---- Uz, Ur convs (input tA = T(h)), accs stay in registers
        v4f az = conv_mfma(Wp + 2u * 73728u, tA, l15, kg8, mt, nq);
        v4f ar = conv_mfma(Wp + 3u * 73728u, tA, l15, kg8, mt, nq);
        __syncthreads();
        // ---- tA = T(wxtp) (tid<512)
        if (tid < 512) {
#pragma unroll
            for (int xx = 0; xx < 8; ++xx) tA[(yy * 8 + xx) * 72 + kk2] = (__bf16)wx8[xx];
        }
        __syncthreads();
        // ---- share conv
        v4f ash = conv_mfma(Wp + 1u * 73728u, tA, l15, kg8, mt, nq);
        // ---- gates (frag domain); rh -> cB
        float zf4[4], wof4[4];
        {
            const int s = nq * 16 + l15;
#pragma unroll
            for (int r = 0; r < 4; ++r) {
                int ko = mt * 16 + kg * 4 + r;
                float wo = ash[r] + sb4[r];
                float z = 1.f / (1.f + expf(-(wo + az[r])));
                float rr = 1.f / (1.f + expf(-(wo + ar[r])));
                cB[ko * 65 + s] = rr * h_s[ko * 64 + s];
                zf4[r] = z;
                wof4[r] = wo;
            }
        }
        __syncthreads();
        // ---- tA = T(rh); zero asum
        {
            int s = tid & 63, g = tid >> 6;
            v4bf hv;
#pragma unroll
            for (int q = 0; q < 4; ++q) hv[q] = (__bf16)cB[(g * 4 + q) * 65 + s];
            *(v4bf*)&tA[s * 72 + g * 4] = hv;
        }
        if (tid < 64) misc[1024 + tid] = 0.f;
        __syncthreads();
        // ---- Uh conv + final update
        {
            v4f ach = conv_mfma(Wp + 4u * 73728u, tA, l15, kg8, mt, nq);
            const int s = nq * 16 + l15;
#pragma unroll
            for (int r = 0; r < 4; ++r) {
                int ko = mt * 16 + kg * 4 + r;
                float hh = tanhf(wof4[r] + ach[r]);
                float hold = h_s[ko * 64 + s];
                float hn = (1.f - zf4[r]) * hh + zf4[r] * hold;
                h_s[ko * 64 + s] = hn;
                hsg[((t * 32 + b) * 64 + ko) * 64 + s] = hn;
                float rsum = hn;
                rsum += __shfl_xor(rsum, 8, 16);
                rsum += __shfl_xor(rsum, 4, 16);
                rsum += __shfl_xor(rsum, 2, 16);
                rsum += __shfl_xor(rsum, 1, 16);
                if (l15 == 0) atomicAdd(&misc[1024 + ko], rsum);
            }
        }
        __syncthreads();
        if (tid < 64) asg[b * 512 + t * 64 + tid] = misc[1024 + tid];
        __syncthreads();
    }
}

// ---------------------------------------------------------------------------
// VLAD: V[b,k,d] = sum_{t,hw} hs*xt - (sum_t asum)*centers. grid (8,32), 256 thr
__global__ __launch_bounds__(256) void k_vlad(const float* __restrict__ centers,
                                              const float* __restrict__ ws,
                                              float* __restrict__ out) {
    __shared__ float As[16 * 68];
    __shared__ float Bs[16 * 68];
    const int b = blockIdx.y;
    const int d0 = blockIdx.x * 64;
    const int tid = threadIdx.x;
    const int kq = tid & 15, dq = tid >> 4;
    const int lk = tid >> 2, q = tid & 3;
    const float* hs = ws + HS_OFF;
    const float* xt = ws + XT_OFF;
    float acc[4][4];
#pragma unroll
    for (int i = 0; i < 4; ++i)
#pragma unroll
        for (int j = 0; j < 4; ++j) acc[i][j] = 0.f;

    for (int rc = 0; rc < 512; rc += 16) {
        int t = rc >> 6, hw0 = rc & 63;
        float4 va = *(const float4*)&hs[((t * 32 + b) * 64 + lk) * 64 + hw0 + q * 4];
        float4 vb = *(const float4*)&xt[(b * 8 + t) * 32768 + (d0 + lk) * 64 + hw0 + q * 4];
        __syncthreads();
        As[(q * 4 + 0) * 68 + lk] = va.x;
        As[(q * 4 + 1) * 68 + lk] = va.y;
        As[(q * 4 + 2) * 68 + lk] = va.z;
        As[(q * 4 + 3) * 68 + lk] = va.w;
        Bs[(q * 4 + 0) * 68 + lk] = vb.x;
        Bs[(q * 4 + 1) * 68 + lk] = vb.y;
        Bs[(q * 4 + 2) * 68 + lk] = vb.z;
        Bs[(q * 4 + 3) * 68 + lk] = vb.w;
        __syncthreads();
#pragma unroll
        for (int cc = 0; cc < 16; ++cc) {
            float4 a = *(const float4*)&As[cc * 68 + kq * 4];
            float4 bb = *(const float4*)&Bs[cc * 68 + dq * 4];
            float av[4] = {a.x, a.y, a.z, a.w};
            float bv[4] = {bb.x, bb.y, bb.z, bb.w};
#pragma unroll
            for (int i = 0; i < 4; ++i)
#pragma unroll
                for (int j = 0; j < 4; ++j)
                    acc[i][j] = fmaf(av[i], bv[j], acc[i][j]);
        }
    }
    const float* asum = ws + ASUM_OFF;
#pragma unroll
    for (int i = 0; i < 4; ++i) {
        int k = kq * 4 + i;
        float at = 0.f;
#pragma unroll
        for (int tp = 0; tp < 8; ++tp) at += asum[b * 512 + tp * 64 + k];
        float4 cen = *(const float4*)&centers[k * 512 + d0 + dq * 4];
        float4 o = {acc[i][0] - at * cen.x, acc[i][1] - at * cen.y,
                    acc[i][2] - at * cen.z, acc[i][3] - at * cen.w};
        *(float4*)&out[b * 32768 + k * 512 + d0 + dq * 4] = o;
    }
}

// ---------------------------------------------------------------------------
__global__ __launch_bounds__(64) void k_norm1(float* __restrict__ out) {
    const int b = blockIdx.x >> 6, k = blockIdx.x & 63;
    float* p = out + b * 32768 + k * 512;
    const int tid = threadIdx.x;
    float v[8];
    float ss = 0.f;
#pragma unroll
    for (int i = 0; i < 8; ++i) {
        v[i] = p[tid + i * 64];
        ss = fmaf(v[i], v[i], ss);
    }
#pragma unroll
    for (int off = 32; off > 0; off >>= 1) ss += __shfl_down(ss, off, 64);
    ss = __shfl(ss, 0, 64);
    float sc = 1.f / fmaxf(sqrtf(ss), 1e-12f);
#pragma unroll
    for (int i = 0; i < 8; ++i) p[tid + i * 64] = v[i] * sc;
}

__global__ __launch_bounds__(256) void k_norm2(float* __restrict__ out) {
    __shared__ float red[4];
    __shared__ float stot;
    const int b = blockIdx.x;
    const int tid = threadIdx.x;
    float* p = out + b * 32768;
    float ss = 0.f;
    for (int i = 0; i < 32; ++i) {
        float4 v = *(const float4*)&p[tid * 4 + i * 1024];
        ss += v.x * v.x + v.y * v.y + v.z * v.z + v.w * v.w;
    }
#pragma unroll
    for (int off = 32; off > 0; off >>= 1) ss += __shfl_down(ss, off, 64);
    if ((tid & 63) == 0) red[tid >> 6] = ss;
    __syncthreads();
    if (tid == 0) stot = 1.f / fmaxf(sqrtf(red[0] + red[1] + red[2] + red[3]), 1e-12f);
    __syncthreads();
    float sc = stot;
    for (int i = 0; i < 32; ++i) {
        float4 v = *(const float4*)&p[tid * 4 + i * 1024];
        v.x *= sc; v.y *= sc; v.z *= sc; v.w *= sc;
        *(float4*)&p[tid * 4 + i * 1024] = v;
    }
}

// ---------------------------------------------------------------------------
extern "C" void kernel_launch(void* const* d_in, const int* in_sizes, int n_in,
                              void* d_out, int out_size, void* d_ws, size_t ws_size,
                              hipStream_t stream) {
    const float* x       = (const float*)d_in[0];
    const float* redu_w  = (const float*)d_in[1];
    const float* redu_b  = (const float*)d_in[2];
    const float* w_x     = (const float*)d_in[3];
    const float* att_x   = (const float*)d_in[4];
    const float* att_h_w = (const float*)d_in[5];
    const float* att_b   = (const float*)d_in[6];
    const float* share_w = (const float*)d_in[7];
    const float* share_b = (const float*)d_in[8];
    const float* U_r     = (const float*)d_in[9];
    const float* U_z     = (const float*)d_in[10];
    const float* U_h     = (const float*)d_in[11];
    const float* centers = (const float*)d_in[12];
    const float* fc1_w   = (const float*)d_in[13];
    const float* fc2_w   = (const float*)d_in[14];
    float* ws = (float*)d_ws;
    float* out = (float*)d_out;

    k_prep<<<dim3(3200), dim3(256), 0, stream>>>(redu_w, w_x, ws);
    k_prep_w<<<dim3(720), dim3(256), 0, stream>>>(att_h_w, share_w, U_z, U_r, U_h, ws);
    k_gemm_xt_mfma<<<dim3(2, 256), dim3(256), 0, stream>>>(x, redu_b, ws);
    k_gemm_wxpb<<<dim3(256), dim3(256), 0, stream>>>(ws);
    k_conv3x3<<<dim3(4, 256), dim3(128), 0, stream>>>(ws + WXPB_OFF, att_x,
                                                      (const float*)nullptr, ws + ATTV_OFF);
    k_recur<<<dim3(32), dim3(1024), 0, stream>>>(att_b, share_b, fc1_w, fc2_w, ws);
    k_vlad<<<dim3(8, 32), dim3(256), 0, stream>>>(centers, ws, out);
    k_norm1<<<dim3(2048), dim3(64), 0, stream>>>(out);
    k_norm2<<<dim3(32), dim3(256), 0, stream>>>(out);
}

// Round 7
// 751.979 us; speedup vs baseline: 1.4894x; 1.4894x over previous
//
#include <hip/hip_runtime.h>
#include <math.h>

// Problem constants
#define T_   8
#define K_   64
#define D_   512
#define CIN_ 1536
#define B_   32
#define S_   64    // H*W = 8*8
#define NT_  256   // B*T

// Workspace layout (float offsets)
#define WLO_BF16  786432u     // bf16-element offset of Wlo within bf16 view
#define WXT_OFF   786432u     // [512][64]  transposed w_x (float offset)
#define XT_OFF    819200u     // [256][512][64]
#define WXPB_OFF  9207808u    // [256][64][64]
#define ATTV_OFF  10256384u   // [256][64][64]  (n = b*8+t)
#define HS_OFF    11436032u   // [8][32][64][64]
#define ASUM_OFF  13041664u   // [32][8][64]
// conv-weight pack (bf16 elements): 5 weights x (hi 36864 + lo 36864),
// layout per weight: [dydx(9)][o(64)][i(64)]. Since R4 only hi halves are read.
#define WPB       25034752u

typedef __bf16 v8bf __attribute__((ext_vector_type(8)));
typedef __bf16 v4bf __attribute__((ext_vector_type(4)));
typedef float  v4f  __attribute__((ext_vector_type(4)));
typedef _Float16 v4h __attribute__((ext_vector_type(4)));
typedef _Float16 v8h __attribute__((ext_vector_type(8)));

// ---------------------------------------------------------------------------
// prep: split redu_w -> bf16 hi/lo, transpose w_x -> wxT[d][k]
__global__ __launch_bounds__(256) void k_prep(const float* __restrict__ redu_w,
                                              const float* __restrict__ w_x,
                                              float* __restrict__ ws) {
    unsigned idx = blockIdx.x * 256u + threadIdx.x;
    if (idx < 786432u) {
        float f = redu_w[idx];
        __bf16 h = (__bf16)f;
        __bf16 l = (__bf16)(f - (float)h);
        __bf16* wb = (__bf16*)ws;
        wb[idx] = h;
        wb[WLO_BF16 + idx] = l;
    } else if (idx < 819200u) {
        unsigned i = idx - 786432u;
        unsigned dd = i >> 6, k = i & 63u;
        ws[WXT_OFF + i] = w_x[k * 512u + dd];
    }
}

// ---------------------------------------------------------------------------
// prep conv weights: [o][i][ky][kx] fp32 -> bf16 hi/lo [dydx][o][i]
__global__ __launch_bounds__(256) void k_prep_w(const float* __restrict__ w0,
                                                const float* __restrict__ w1,
                                                const float* __restrict__ w2,
                                                const float* __restrict__ w3,
                                                const float* __restrict__ w4,
                                                float* __restrict__ ws) {
    unsigned idx = blockIdx.x * 256u + threadIdx.x;
    if (idx >= 184320u) return;
    unsigned w = idx / 36864u, r = idx % 36864u;
    const float* src = (w == 0) ? w0 : (w == 1) ? w1 : (w == 2) ? w2 : (w == 3) ? w3 : w4;
    float f = src[r];
    __bf16 h = (__bf16)f;
    __bf16 l = (__bf16)(f - (float)h);
    unsigned o = r / 576u, rem = r % 576u, ii = rem / 9u, dydx = rem % 9u;
    __bf16* wb = (__bf16*)ws;
    unsigned dst = WPB + w * 73728u + (dydx * 64u + o) * 64u + ii;
    wb[dst] = h;
    wb[dst + 36864u] = l;
}

// ---------------------------------------------------------------------------
// xt = redu_w @ x + redu_b via bf16 hi/lo split MFMA (3 products).
__global__ __launch_bounds__(256) void k_gemm_xt_mfma(const float* __restrict__ x,
                                                      const float* __restrict__ redu_b,
                                                      float* __restrict__ ws) {
    __shared__ __bf16 xhi_s[64 * 72];
    __shared__ __bf16 xlo_s[64 * 72];
    const __bf16* __restrict__ Whi = (const __bf16*)ws;
    const __bf16* __restrict__ Wlo = ((const __bf16*)ws) + WLO_BF16;
    float* xt = ws + XT_OFF;
    const int n = blockIdx.y;
    const int d0 = blockIdx.x * 256;
    const int tid = threadIdx.x;
    const int wave = tid >> 6, lane = tid & 63;
    const int lrow = lane & 15, lkg = lane >> 4;
    const int m_base = d0 + wave * 64;
    const float* __restrict__ xn = x + n * 98304;
    const int s4 = tid & 15, cb = tid >> 4;

    v4f acc[4][4];
#pragma unroll
    for (int mt = 0; mt < 4; ++mt)
#pragma unroll
        for (int nt = 0; nt < 4; ++nt) acc[mt][nt] = (v4f){0.f, 0.f, 0.f, 0.f};

    for (int c0 = 0; c0 < 1536; c0 += 64) {
        float4 v[4];
#pragma unroll
        for (int j = 0; j < 4; ++j)
            v[j] = *(const float4*)&xn[(c0 + cb * 4 + j) * 64 + s4 * 4];
        __syncthreads();
#pragma unroll
        for (int i = 0; i < 4; ++i) {
            v4bf hv, lv;
#pragma unroll
            for (int j = 0; j < 4; ++j) {
                float f = ((const float*)&v[j])[i];
                __bf16 h = (__bf16)f;
                hv[j] = h;
                lv[j] = (__bf16)(f - (float)h);
            }
            int row = s4 * 4 + i;
            *(v4bf*)&xhi_s[row * 72 + cb * 4] = hv;
            *(v4bf*)&xlo_s[row * 72 + cb * 4] = lv;
        }
        __syncthreads();
#pragma unroll
        for (int ks = 0; ks < 64; ks += 32) {
            v8bf bh[4], bl[4], ah[4], al[4];
#pragma unroll
            for (int nt = 0; nt < 4; ++nt) {
                int off = (nt * 16 + lrow) * 72 + ks + lkg * 8;
                bh[nt] = *(const v8bf*)&xhi_s[off];
                bl[nt] = *(const v8bf*)&xlo_s[off];
            }
#pragma unroll
            for (int mt = 0; mt < 4; ++mt) {
                int gi = (m_base + mt * 16 + lrow) * 1536 + c0 + ks + lkg * 8;
                ah[mt] = *(const v8bf*)&Whi[gi];
                al[mt] = *(const v8bf*)&Wlo[gi];
            }
#pragma unroll
            for (int mt = 0; mt < 4; ++mt)
#pragma unroll
                for (int nt = 0; nt < 4; ++nt) {
                    acc[mt][nt] = __builtin_amdgcn_mfma_f32_16x16x32_bf16(
                        ah[mt], bh[nt], acc[mt][nt], 0, 0, 0);
                    acc[mt][nt] = __builtin_amdgcn_mfma_f32_16x16x32_bf16(
                        ah[mt], bl[nt], acc[mt][nt], 0, 0, 0);
                    acc[mt][nt] = __builtin_amdgcn_mfma_f32_16x16x32_bf16(
                        al[mt], bh[nt], acc[mt][nt], 0, 0, 0);
                }
        }
    }
#pragma unroll
    for (int mt = 0; mt < 4; ++mt) {
#pragma unroll
        for (int r = 0; r < 4; ++r) {
            int m = m_base + mt * 16 + lkg * 4 + r;
            float bias = redu_b[m];
#pragma unroll
            for (int nt = 0; nt < 4; ++nt) {
                int s = nt * 16 + lrow;
                xt[(n * 512 + m) * 64 + s] = acc[mt][nt][r] + bias;
            }
        }
    }
}

// ---------------------------------------------------------------------------
// wxpb = w_x @ xt ; per n: (64x512)@(512x64). grid 256, block 256, 4x4/thread.
__global__ __launch_bounds__(256) void k_gemm_wxpb(float* __restrict__ ws) {
    __shared__ float Aw[16 * 64];
    __shared__ float Bx[16 * 64];
    const float* wxT = ws + WXT_OFF;
    const float* xt = ws + XT_OFF;
    float* wxpb = ws + WXPB_OFF;
    const int n = blockIdx.x;
    const int tid = threadIdx.x;
    const int sg = tid & 15, kg = tid >> 4;

    float acc[4][4];
#pragma unroll
    for (int i = 0; i < 4; ++i)
#pragma unroll
        for (int j = 0; j < 4; ++j) acc[i][j] = 0.f;

    for (int d0 = 0; d0 < 512; d0 += 16) {
        int cc = tid >> 4, q = tid & 15;
        *(float4*)&Aw[cc * 64 + q * 4] = *(const float4*)&wxT[(d0 + cc) * 64 + q * 4];
        *(float4*)&Bx[cc * 64 + q * 4] = *(const float4*)&xt[n * 32768 + (d0 + cc) * 64 + q * 4];
        __syncthreads();
#pragma unroll
        for (int c2 = 0; c2 < 16; ++c2) {
            float4 a = *(const float4*)&Aw[c2 * 64 + kg * 4];
            float4 b = *(const float4*)&Bx[c2 * 64 + sg * 4];
            float av[4] = {a.x, a.y, a.z, a.w};
            float bv[4] = {b.x, b.y, b.z, b.w};
#pragma unroll
            for (int i = 0; i < 4; ++i)
#pragma unroll
                for (int j = 0; j < 4; ++j)
                    acc[i][j] = fmaf(av[i], bv[j], acc[i][j]);
        }
        __syncthreads();
    }
#pragma unroll
    for (int i = 0; i < 4; ++i) {
        float4 o = {acc[i][0], acc[i][1], acc[i][2], acc[i][3]};
        *(float4*)&wxpb[(n * 64 + kg * 4 + i) * 64 + sg * 4] = o;
    }
}

// ---------------------------------------------------------------------------
// generic 3x3 conv (fp32), used only for attv (256 parallel images).
__global__ __launch_bounds__(128) void k_conv3x3(const float* __restrict__ in,
                                                 const float* __restrict__ wt,
                                                 const float* __restrict__ bias,
                                                 float* __restrict__ out) {
    __shared__ float in_s[4096];
    __shared__ float w_s[16 * 576];
    const int img = blockIdx.y;
    const int k0 = blockIdx.x * 16;
    const int tid = threadIdx.x;
    const int kl = tid >> 3, y = tid & 7;
#pragma unroll
    for (int i = 0; i < 8; ++i) {
        int f = tid + i * 128;
        *(float4*)&in_s[f * 4] = *(const float4*)&in[img * 4096 + f * 4];
    }
#pragma unroll
    for (int i = 0; i < 18; ++i) {
        int f = tid + i * 128;
        *(float4*)&w_s[f * 4] = *(const float4*)&wt[k0 * 576 + f * 4];
    }
    __syncthreads();
    float o[8];
#pragma unroll
    for (int xx = 0; xx < 8; ++xx) o[xx] = 0.f;
    for (int kp = 0; kp < 64; ++kp) {
        const float* wp = &w_s[kl * 576 + kp * 9];
        float wv[9];
#pragma unroll
        for (int q = 0; q < 9; ++q) wv[q] = wp[q];
#pragma unroll
        for (int dy = 0; dy < 3; ++dy) {
            int yy = y + dy - 1;
            if (yy >= 0 && yy < 8) {
                float4 ra = *(const float4*)&in_s[kp * 64 + yy * 8];
                float4 rb = *(const float4*)&in_s[kp * 64 + yy * 8 + 4];
                float r[8] = {ra.x, ra.y, ra.z, ra.w, rb.x, rb.y, rb.z, rb.w};
                float wa = wv[dy * 3 + 0], wb = wv[dy * 3 + 1], wc = wv[dy * 3 + 2];
#pragma unroll
                for (int xx = 0; xx < 8; ++xx) {
                    float t = wb * r[xx];
                    if (xx > 0) t += wa * r[xx - 1];
                    if (xx < 7) t += wc * r[xx + 1];
                    o[xx] += t;
                }
            }
        }
    }
    float bv = bias ? bias[k0 + kl] : 0.f;
    float4 o0 = {o[0] + bv, o[1] + bv, o[2] + bv, o[3] + bv};
    float4 o1 = {o[4] + bv, o[5] + bv, o[6] + bv, o[7] + bv};
    *(float4*)&out[img * 4096 + (k0 + kl) * 64 + y * 8] = o0;
    *(float4*)&out[img * 4096 + (k0 + kl) * 64 + y * 8 + 4] = o1;
}

// ---------------------------------------------------------------------------
// Single 3x3 conv as 9 shifted MFMA GEMMs (R4 form: 8 waves, acc[2],
// single-bf16 weights, per-dy 6-fragment batch).
__device__ __forceinline__ void conv_mfma(const __bf16* __restrict__ Wh,
                                          const __bf16* tS,
                                          int l15, int kg8, int mt, int ntb,
                                          v4f acc[2]) {
    v8bf vz;
#pragma unroll
    for (int q = 0; q < 8; ++q) vz[q] = (__bf16)0.f;
    v4f a0 = (v4f){0.f, 0.f, 0.f, 0.f};
    v4f a1 = (v4f){0.f, 0.f, 0.f, 0.f};
    const int n0 = ntb * 16 + l15;
#pragma unroll
    for (int dy = 0; dy < 3; ++dy) {
        v8bf wh[3][2];
#pragma unroll
        for (int dx = 0; dx < 3; ++dx) {
            const int wrow = ((dy * 3 + dx) * 64 + mt * 16 + l15) * 64 + kg8;
#pragma unroll
            for (int kci = 0; kci < 2; ++kci)
                wh[dx][kci] = *(const v8bf*)&Wh[wrow + kci * 32];
        }
#pragma unroll
        for (int dx = 0; dx < 3; ++dx) {
            const int y0 = (n0 >> 3) + dy - 1, x0 = (n0 & 7) + dx - 1;
            const bool okx = (unsigned)x0 < 8u;
            const bool ok0 = ((unsigned)y0 < 8u) & okx;
            const bool ok1 = ((unsigned)(y0 + 2) < 8u) & okx;
            const int s0 = ((y0 * 8 + x0) & 63) * 72 + kg8;
            const int s1 = (((y0 + 2) * 8 + x0) & 63) * 72 + kg8;
#pragma unroll
            for (int kci = 0; kci < 2; ++kci) {
                v8bf b0 = ok0 ? *(const v8bf*)&tS[s0 + kci * 32] : vz;
                v8bf b1 = ok1 ? *(const v8bf*)&tS[s1 + kci * 32] : vz;
                a0 = __builtin_amdgcn_mfma_f32_16x16x32_bf16(wh[dx][kci], b0, a0, 0, 0, 0);
                a1 = __builtin_amdgcn_mfma_f32_16x16x32_bf16(wh[dx][kci], b1, a1, 0, 0, 0);
            }
        }
    }
    acc[0] = a0;
    acc[1] = a1;
}

// ---------------------------------------------------------------------------
// R7: fused triple conv over the SAME input tA = T(h): ah (W0), az (W1),
// ar (W2). Each tA fragment is read from LDS ONCE and feeds 3 MFMAs -> LDS
// reads per step drop 180->108 and the three weight streams interleave as one
// wide in-flight group. Transient live set ~70 VGPRs (6 acc + 6 w + 2 b +
// addresses) — legal under the hard 128 cap only because wxv is gone.
__device__ __forceinline__ void conv_mfma3(const __bf16* __restrict__ W0,
                                           const __bf16* __restrict__ W1,
                                           const __bf16* __restrict__ W2,
                                           const __bf16* tS,
                                           int l15, int kg8, int mt, int ntb,
                                           v4f a0[2], v4f a1[2], v4f a2[2]) {
    v8bf vz;
#pragma unroll
    for (int q = 0; q < 8; ++q) vz[q] = (__bf16)0.f;
#pragma unroll
    for (int i = 0; i < 2; ++i) {
        a0[i] = (v4f){0.f, 0.f, 0.f, 0.f};
        a1[i] = (v4f){0.f, 0.f, 0.f, 0.f};
        a2[i] = (v4f){0.f, 0.f, 0.f, 0.f};
    }
    const int n0 = ntb * 16 + l15;
#pragma unroll
    for (int dy = 0; dy < 3; ++dy) {
#pragma unroll
        for (int dx = 0; dx < 3; ++dx) {
            const int wrow = ((dy * 3 + dx) * 64 + mt * 16 + l15) * 64 + kg8;
            v8bf w0[2], w1[2], w2[2];
#pragma unroll
            for (int kci = 0; kci < 2; ++kci) {
                w0[kci] = *(const v8bf*)&W0[wrow + kci * 32];
                w1[kci] = *(const v8bf*)&W1[wrow + kci * 32];
                w2[kci] = *(const v8bf*)&W2[wrow + kci * 32];
            }
            const int y0 = (n0 >> 3) + dy - 1, x0 = (n0 & 7) + dx - 1;
            const bool okx = (unsigned)x0 < 8u;
            const bool ok0 = ((unsigned)y0 < 8u) & okx;
            const bool ok1 = ((unsigned)(y0 + 2) < 8u) & okx;
            const int s0 = ((y0 * 8 + x0) & 63) * 72 + kg8;
            const int s1 = (((y0 + 2) * 8 + x0) & 63) * 72 + kg8;
#pragma unroll
            for (int kci = 0; kci < 2; ++kci) {
                v8bf b0 = ok0 ? *(const v8bf*)&tS[s0 + kci * 32] : vz;
                v8bf b1 = ok1 ? *(const v8bf*)&tS[s1 + kci * 32] : vz;
                a0[0] = __builtin_amdgcn_mfma_f32_16x16x32_bf16(w0[kci], b0, a0[0], 0, 0, 0);
                a0[1] = __builtin_amdgcn_mfma_f32_16x16x32_bf16(w0[kci], b1, a0[1], 0, 0, 0);
                a1[0] = __builtin_amdgcn_mfma_f32_16x16x32_bf16(w1[kci], b0, a1[0], 0, 0, 0);
                a1[1] = __builtin_amdgcn_mfma_f32_16x16x32_bf16(w1[kci], b1, a1[1], 0, 0, 0);
                a2[0] = __builtin_amdgcn_mfma_f32_16x16x32_bf16(w2[kci], b0, a2[0], 0, 0, 0);
                a2[1] = __builtin_amdgcn_mfma_f32_16x16x32_bf16(w2[kci], b1, a2[1], 0, 0, 0);
            }
        }
    }
}

__device__ __forceinline__ void write_c(float* c, const v4f acc[2],
                                        int l15, int kg, int mt, int ntb) {
#pragma unroll
    for (int i = 0; i < 2; ++i)
#pragma unroll
        for (int r = 0; r < 4; ++r)
            c[(mt * 16 + kg * 4 + r) * 65 + (ntb + i) * 16 + l15] = acc[i][r];
}

// ---------------------------------------------------------------------------
// Whole recurrence in one kernel: grid 32 (one block per b), 512 threads.
// h lives in LDS across all 8 steps; convs on MFMA.
// R4: single-bf16 conv weights (best verified config, 372 us).
// R7: (a) wxv reg-hoist DROPPED for good — the 64 permanent VGPRs were the
// source of the residual ~13 MB spill traffic under the hard 128-VGPR cap
// (cap confirmed structural in R6: allocator targets 2 blocks/CU always,
// 512thr->128, 1024thr->64, all attributes inert). wxtp reads wxpb from
// global; L2-resident since R4. (b) ah/Uz/Ur convs fused into conv_mfma3
// (shared T(h) input): LDS reads 180->108/step, az/ar ride in registers
// across the low-pressure e/fc phases.
__global__ __launch_bounds__(512) void k_recur(const float* __restrict__ att_b,
                                               const float* __restrict__ share_b,
                                               const float* __restrict__ fc1_w,
                                               const float* __restrict__ fc2_w,
                                               float* __restrict__ ws) {
    __shared__ float h_s[4096];                                   // h [k][s]
    __shared__ __attribute__((aligned(16))) __bf16 tA[64 * 72];   // T(in) [s][kp]
    __shared__ float cA[64 * 65];                                 // conv out / scratch
    __shared__ float cB[64 * 65];
    __shared__ float misc[1088];  // em|exs [0..511], ex|als [512..1023], h1|asum [1024..]
    __shared__ __attribute__((aligned(16))) _Float16 attv_s[32768];  // [tp][k][s] fp16
    const int b = blockIdx.x, tid = threadIdx.x;
    const int lane = tid & 63;
    const int wave = tid >> 6, mt = wave >> 1, ntb = (wave & 1) * 2;
    const int l15 = lane & 15, kg = lane >> 4, kg8 = kg * 8;
    const int kk = tid >> 3, yy = tid & 7;
    const __bf16* Wp = (const __bf16*)ws + WPB;
    const float* attv = ws + ATTV_OFF;
    const float* wxpb = ws + WXPB_OFF;
    float* hsg = ws + HS_OFF;
    float* asg = ws + ASUM_OFF;

    // ---- one-time: stage attv (this b) into LDS as fp16
    {
        const float* src = attv + b * 32768;
        for (int i = tid; i < 8192; i += 512) {
            float4 v = *(const float4*)&src[i * 4];
            v4h h4 = {(_Float16)v.x, (_Float16)v.y, (_Float16)v.z, (_Float16)v.w};
            *(v4h*)&attv_s[i * 4] = h4;
        }
    }

    for (int i = tid; i < 4096; i += 512) h_s[i] = 0.f;
    const float abv = att_b[kk];
    float sb4[4];
#pragma unroll
    for (int r = 0; r < 4; ++r) sb4[r] = share_b[mt * 16 + kg * 4 + r];
    __syncthreads();

    for (int t = 0; t < 8; ++t) {
        // ---- tA = T(h)
        {
            int s = tid & 63, g = tid >> 6;
#pragma unroll
            for (int q4 = 0; q4 < 2; ++q4) {
                v4bf hv;
#pragma unroll
                for (int q = 0; q < 4; ++q) hv[q] = (__bf16)h_s[(g * 8 + q4 * 4 + q) * 64 + s];
                *(v4bf*)&tA[s * 72 + g * 8 + q4 * 4] = hv;
            }
        }
        __syncthreads();
        // ---- fused ah/Uz/Ur convs: ah -> cA; az, ar stay in registers
        v4f az[2], ar[2];
        {
            v4f a[2];
            conv_mfma3(Wp, Wp + 2u * 73728u, Wp + 3u * 73728u, tA,
                       l15, kg8, mt, ntb, a, az, ar);
            write_c(cA, a, l15, kg, mt, ntb);
        }
        __syncthreads();
        // ---- e = relu(attv+ah); mean/max over s -> em/ex  (attv from LDS fp16)
        {
            float ah8[8];
            const float* cr = &cA[kk * 65 + yy * 8];
#pragma unroll
            for (int xx = 0; xx < 8; ++xx) ah8[xx] = cr[xx] + abv;
            for (int tp = 0; tp < 8; ++tp) {
                v8h va = *(const v8h*)&attv_s[tp * 4096 + kk * 64 + yy * 8];
                float s_ = 0.f, m_ = 0.f;
#pragma unroll
                for (int xx = 0; xx < 8; ++xx) {
                    float v = fmaxf((float)va[xx] + ah8[xx], 0.f);
                    s_ += v;
                    m_ = fmaxf(m_, v);
                }
                s_ += __shfl_down(s_, 4, 8);
                s_ += __shfl_down(s_, 2, 8);
                s_ += __shfl_down(s_, 1, 8);
                m_ = fmaxf(m_, __shfl_down(m_, 4, 8));
                m_ = fmaxf(m_, __shfl_down(m_, 2, 8));
                m_ = fmaxf(m_, __shfl_down(m_, 1, 8));
                if (yy == 0) {
                    misc[tp * 64 + kk] = s_ * (1.f / 64.f);
                    misc[512 + tp * 64 + kk] = m_;
                }
            }
        }
        __syncthreads();
        // ---- fc1 (rows 0..31 mean path, 32..63 max path), float4 loads
        {
            int i2 = tid >> 3, part = tid & 7;
            int i = i2 & 31;
            const float* src = misc + ((i2 < 32) ? 0 : 512);
            const float* wrow = fc1_w + i * 512 + part * 64;
            const float* s2 = src + part * 64;
            float p = 0.f;
#pragma unroll
            for (int c4 = 0; c4 < 16; ++c4) {
                float4 wv = *(const float4*)&wrow[c4 * 4];
                float4 sv = *(const float4*)&s2[c4 * 4];
                p = fmaf(wv.x, sv.x, p);
                p = fmaf(wv.y, sv.y, p);
                p = fmaf(wv.z, sv.z, p);
                p = fmaf(wv.w, sv.w, p);
            }
            p += __shfl_down(p, 4, 8);
            p += __shfl_down(p, 2, 8);
            p += __shfl_down(p, 1, 8);
            if (part == 0) misc[1024 + i2] = fmaxf(p, 0.f);
        }
        __syncthreads();
        // ---- fc2 + tanh + exp -> exs at misc[0..511], float4 loads
        {
            const float* w2 = fc2_w + tid * 32;
            float gm = 0.f, gx = 0.f;
#pragma unroll
            for (int i4 = 0; i4 < 8; ++i4) {
                float4 wv = *(const float4*)&w2[i4 * 4];
                gm = fmaf(wv.x, misc[1024 + i4 * 4 + 0], gm);
                gm = fmaf(wv.y, misc[1024 + i4 * 4 + 1], gm);
                gm = fmaf(wv.z, misc[1024 + i4 * 4 + 2], gm);
                gm = fmaf(wv.w, misc[1024 + i4 * 4 + 3], gm);
                gx = fmaf(wv.x, misc[1056 + i4 * 4 + 0], gx);
                gx = fmaf(wv.y, misc[1056 + i4 * 4 + 1], gx);
                gx = fmaf(wv.z, misc[1056 + i4 * 4 + 2], gx);
                gx = fmaf(wv.w, misc[1056 + i4 * 4 + 3], gx);
            }
            misc[tid] = expf(tanhf(gm + gx));
        }
        __syncthreads();
        // ---- softmax over T -> als at misc[512..1023]
        {
            int k6 = tid & 63;
            float den = 0.f;
#pragma unroll
            for (int tp = 0; tp < 8; ++tp) den += misc[tp * 64 + k6];
            den += (den == 0.f) ? 1.f : 0.f;
            misc[512 + tid] = misc[tid] / den;
        }
        __syncthreads();
        // ---- wxtp: read wxpb from global (L2-resident), weighted by als;
        //      then tA = T(wxtp) (tA free: conv_mfma3 consumed it phases ago)
        {
            float wx8[8];
#pragma unroll
            for (int xx = 0; xx < 8; ++xx) wx8[xx] = 0.f;
            const float* src0 = wxpb + b * 32768 + kk * 64 + yy * 8;
#pragma unroll
            for (int tp = 0; tp < 8; ++tp) {
                float al = misc[512 + tp * 64 + kk];
                float4 v0 = *(const float4*)&src0[tp * 4096];
                float4 v1 = *(const float4*)&src0[tp * 4096 + 4];
                float v[8] = {v0.x, v0.y, v0.z, v0.w, v1.x, v1.y, v1.z, v1.w};
#pragma unroll
                for (int xx = 0; xx < 8; ++xx) wx8[xx] = fmaf(al, v[xx], wx8[xx]);
            }
#pragma unroll
            for (int xx = 0; xx < 8; ++xx) tA[(yy * 8 + xx) * 72 + kk] = (__bf16)wx8[xx];
        }
        __syncthreads();
        // ---- share conv
        v4f ash[2];
        conv_mfma(Wp + 1u * 73728u, tA, l15, kg8, mt, ntb, ash);
        // ---- gates (frag domain); rh -> cB
        float zf[2][4], wof[2][4];
#pragma unroll
        for (int i = 0; i < 2; ++i)
#pragma unroll
            for (int r = 0; r < 4; ++r) {
                int ko = mt * 16 + kg * 4 + r;
                int s = (ntb + i) * 16 + l15;
                float wo = ash[i][r] + sb4[r];
                float z = 1.f / (1.f + expf(-(wo + az[i][r])));
                float rr = 1.f / (1.f + expf(-(wo + ar[i][r])));
                cB[ko * 65 + s] = rr * h_s[ko * 64 + s];
                zf[i][r] = z;
                wof[i][r] = wo;
            }
        __syncthreads();
        // ---- tA = T(rh); zero asum
        {
            int s = tid & 63, g = tid >> 6;
#pragma unroll
            for (int q4 = 0; q4 < 2; ++q4) {
                v4bf hv;
#pragma unroll
                for (int q = 0; q < 4; ++q) hv[q] = (__bf16)cB[(g * 8 + q4 * 4 + q) * 65 + s];
                *(v4bf*)&tA[s * 72 + g * 8 + q4 * 4] = hv;
            }
        }
        if (tid < 64) misc[1024 + tid] = 0.f;
        __syncthreads();
        // ---- Uh conv + final update
        v4f ach[2];
        conv_mfma(Wp + 4u * 73728u, tA, l15, kg8, mt, ntb, ach);
#pragma unroll
        for (int r = 0; r < 4; ++r) {
            int ko = mt * 16 + kg * 4 + r;
            float rsum = 0.f;
#pragma unroll
            for (int i = 0; i < 2; ++i) {
                int s = (ntb + i) * 16 + l15;
                float hh = tanhf(wof[i][r] + ach[i][r]);
                float hold = h_s[ko * 64 + s];
                float hn = (1.f - zf[i][r]) * hh + zf[i][r] * hold;
                h_s[ko * 64 + s] = hn;
                hsg[((t * 32 + b) * 64 + ko) * 64 + s] = hn;
                rsum += hn;
            }
            rsum += __shfl_xor(rsum, 8, 16);
            rsum += __shfl_xor(rsum, 4, 16);
            rsum += __shfl_xor(rsum, 2, 16);
            rsum += __shfl_xor(rsum, 1, 16);
            if (l15 == 0) atomicAdd(&misc[1024 + ko], rsum);
        }
        __syncthreads();
        if (tid < 64) asg[b * 512 + t * 64 + tid] = misc[1024 + tid];
        __syncthreads();
    }
}

// ---------------------------------------------------------------------------
// VLAD: V[b,k,d] = sum_{t,hw} hs*xt - (sum_t asum)*centers. grid (8,32), 256 thr
__global__ __launch_bounds__(256) void k_vlad(const float* __restrict__ centers,
                                              const float* __restrict__ ws,
                                              float* __restrict__ out) {
    __shared__ float As[16 * 68];
    __shared__ float Bs[16 * 68];
    const int b = blockIdx.y;
    const int d0 = blockIdx.x * 64;
    const int tid = threadIdx.x;
    const int kq = tid & 15, dq = tid >> 4;
    const int lk = tid >> 2, q = tid & 3;
    const float* hs = ws + HS_OFF;
    const float* xt = ws + XT_OFF;
    float acc[4][4];
#pragma unroll
    for (int i = 0; i < 4; ++i)
#pragma unroll
        for (int j = 0; j < 4; ++j) acc[i][j] = 0.f;

    for (int rc = 0; rc < 512; rc += 16) {
        int t = rc >> 6, hw0 = rc & 63;
        float4 va = *(const float4*)&hs[((t * 32 + b) * 64 + lk) * 64 + hw0 + q * 4];
        float4 vb = *(const float4*)&xt[(b * 8 + t) * 32768 + (d0 + lk) * 64 + hw0 + q * 4];
        __syncthreads();
        As[(q * 4 + 0) * 68 + lk] = va.x;
        As[(q * 4 + 1) * 68 + lk] = va.y;
        As[(q * 4 + 2) * 68 + lk] = va.z;
        As[(q * 4 + 3) * 68 + lk] = va.w;
        Bs[(q * 4 + 0) * 68 + lk] = vb.x;
        Bs[(q * 4 + 1) * 68 + lk] = vb.y;
        Bs[(q * 4 + 2) * 68 + lk] = vb.z;
        Bs[(q * 4 + 3) * 68 + lk] = vb.w;
        __syncthreads();
#pragma unroll
        for (int cc = 0; cc < 16; ++cc) {
            float4 a = *(const float4*)&As[cc * 68 + kq * 4];
            float4 bb = *(const float4*)&Bs[cc * 68 + dq * 4];
            float av[4] = {a.x, a.y, a.z, a.w};
            float bv[4] = {bb.x, bb.y, bb.z, bb.w};
#pragma unroll
            for (int i = 0; i < 4; ++i)
#pragma unroll
                for (int j = 0; j < 4; ++j)
                    acc[i][j] = fmaf(av[i], bv[j], acc[i][j]);
        }
    }
    const float* asum = ws + ASUM_OFF;
#pragma unroll
    for (int i = 0; i < 4; ++i) {
        int k = kq * 4 + i;
        float at = 0.f;
#pragma unroll
        for (int tp = 0; tp < 8; ++tp) at += asum[b * 512 + tp * 64 + k];
        float4 cen = *(const float4*)&centers[k * 512 + d0 + dq * 4];
        float4 o = {acc[i][0] - at * cen.x, acc[i][1] - at * cen.y,
                    acc[i][2] - at * cen.z, acc[i][3] - at * cen.w};
        *(float4*)&out[b * 32768 + k * 512 + d0 + dq * 4] = o;
    }
}

// ---------------------------------------------------------------------------
__global__ __launch_bounds__(64) void k_norm1(float* __restrict__ out) {
    const int b = blockIdx.x >> 6, k = blockIdx.x & 63;
    float* p = out + b * 32768 + k * 512;
    const int tid = threadIdx.x;
    float v[8];
    float ss = 0.f;
#pragma unroll
    for (int i = 0; i < 8; ++i) {
        v[i] = p[tid + i * 64];
        ss = fmaf(v[i], v[i], ss);
    }
#pragma unroll
    for (int off = 32; off > 0; off >>= 1) ss += __shfl_down(ss, off, 64);
    ss = __shfl(ss, 0, 64);
    float sc = 1.f / fmaxf(sqrtf(ss), 1e-12f);
#pragma unroll
    for (int i = 0; i < 8; ++i) p[tid + i * 64] = v[i] * sc;
}

__global__ __launch_bounds__(256) void k_norm2(float* __restrict__ out) {
    __shared__ float red[4];
    __shared__ float stot;
    const int b = blockIdx.x;
    const int tid = threadIdx.x;
    float* p = out + b * 32768;
    float ss = 0.f;
    for (int i = 0; i < 32; ++i) {
        float4 v = *(const float4*)&p[tid * 4 + i * 1024];
        ss += v.x * v.x + v.y * v.y + v.z * v.z + v.w * v.w;
    }
#pragma unroll
    for (int off = 32; off > 0; off >>= 1) ss += __shfl_down(ss, off, 64);
    if ((tid & 63) == 0) red[tid >> 6] = ss;
    __syncthreads();
    if (tid == 0) stot = 1.f / fmaxf(sqrtf(red[0] + red[1] + red[2] + red[3]), 1e-12f);
    __syncthreads();
    float sc = stot;
    for (int i = 0; i < 32; ++i) {
        float4 v = *(const float4*)&p[tid * 4 + i * 1024];
        v.x *= sc; v.y *= sc; v.z *= sc; v.w *= sc;
        *(float4*)&p[tid * 4 + i * 1024] = v;
    }
}

// ---------------------------------------------------------------------------
extern "C" void kernel_launch(void* const* d_in, const int* in_sizes, int n_in,
                              void* d_out, int out_size, void* d_ws, size_t ws_size,
                              hipStream_t stream) {
    const float* x       = (const float*)d_in[0];
    const float* redu_w  = (const float*)d_in[1];
    const float* redu_b  = (const float*)d_in[2];
    const float* w_x     = (const float*)d_in[3];
    const float* att_x   = (const float*)d_in[4];
    const float* att_h_w = (const float*)d_in[5];
    const float* att_b   = (const float*)d_in[6];
    const float* share_w = (const float*)d_in[7];
    const float* share_b = (const float*)d_in[8];
    const float* U_r     = (const float*)d_in[9];
    const float* U_z     = (const float*)d_in[10];
    const float* U_h     = (const float*)d_in[11];
    const float* centers = (const float*)d_in[12];
    const float* fc1_w   = (const float*)d_in[13];
    const float* fc2_w   = (const float*)d_in[14];
    float* ws = (float*)d_ws;
    float* out = (float*)d_out;

    k_prep<<<dim3(3200), dim3(256), 0, stream>>>(redu_w, w_x, ws);
    k_prep_w<<<dim3(720), dim3(256), 0, stream>>>(att_h_w, share_w, U_z, U_r, U_h, ws);
    k_gemm_xt_mfma<<<dim3(2, 256), dim3(256), 0, stream>>>(x, redu_b, ws);
    k_gemm_wxpb<<<dim3(256), dim3(256), 0, stream>>>(ws);
    k_conv3x3<<<dim3(4, 256), dim3(128), 0, stream>>>(ws + WXPB_OFF, att_x,
                                                      (const float*)nullptr, ws + ATTV_OFF);
    k_recur<<<dim3(32), dim3(512), 0, stream>>>(att_b, share_b, fc1_w, fc2_w, ws);
    k_vlad<<<dim3(8, 32), dim3(256), 0, stream>>>(centers, ws, out);
    k_norm1<<<dim3(2048), dim3(64), 0, stream>>>(out);
    k_norm2<<<dim3(32), dim3(256), 0, stream>>>(out);
}

// Round 8
// 737.685 us; speedup vs baseline: 1.5182x; 1.0194x over previous
//
#include <hip/hip_runtime.h>
#include <math.h>

// Problem constants
#define T_   8
#define K_   64
#define D_   512
#define CIN_ 1536
#define B_   32
#define S_   64    // H*W = 8*8
#define NT_  256   // B*T

// Workspace layout (float offsets)
#define WLO_BF16  786432u     // bf16-element offset of Wlo within bf16 view
#define WXT_OFF   786432u     // [512][64]  transposed w_x (float offset)
#define XT_OFF    819200u     // [256][512][64]
#define WXPB_OFF  9207808u    // [256][64][64]
#define ATTV_OFF  10256384u   // [256][64][64]  (n = b*8+t)
#define HS_OFF    11436032u   // [8][32][64][64]
#define ASUM_OFF  13041664u   // [32][8][64]
// conv-weight pack (bf16 elements): 5 weights x (hi 36864 + lo 36864),
// layout per weight: [dydx(9)][o(64)][i(64)]. Since R4 only hi halves are read.
#define WPB       25034752u

typedef __bf16 v8bf __attribute__((ext_vector_type(8)));
typedef __bf16 v4bf __attribute__((ext_vector_type(4)));
typedef float  v4f  __attribute__((ext_vector_type(4)));
typedef _Float16 v4h __attribute__((ext_vector_type(4)));
typedef _Float16 v8h __attribute__((ext_vector_type(8)));

// ---------------------------------------------------------------------------
// prep: split redu_w -> bf16 hi/lo, transpose w_x -> wxT[d][k]
__global__ __launch_bounds__(256) void k_prep(const float* __restrict__ redu_w,
                                              const float* __restrict__ w_x,
                                              float* __restrict__ ws) {
    unsigned idx = blockIdx.x * 256u + threadIdx.x;
    if (idx < 786432u) {
        float f = redu_w[idx];
        __bf16 h = (__bf16)f;
        __bf16 l = (__bf16)(f - (float)h);
        __bf16* wb = (__bf16*)ws;
        wb[idx] = h;
        wb[WLO_BF16 + idx] = l;
    } else if (idx < 819200u) {
        unsigned i = idx - 786432u;
        unsigned dd = i >> 6, k = i & 63u;
        ws[WXT_OFF + i] = w_x[k * 512u + dd];
    }
}

// ---------------------------------------------------------------------------
// prep conv weights: [o][i][ky][kx] fp32 -> bf16 hi/lo [dydx][o][i]
__global__ __launch_bounds__(256) void k_prep_w(const float* __restrict__ w0,
                                                const float* __restrict__ w1,
                                                const float* __restrict__ w2,
                                                const float* __restrict__ w3,
                                                const float* __restrict__ w4,
                                                float* __restrict__ ws) {
    unsigned idx = blockIdx.x * 256u + threadIdx.x;
    if (idx >= 184320u) return;
    unsigned w = idx / 36864u, r = idx % 36864u;
    const float* src = (w == 0) ? w0 : (w == 1) ? w1 : (w == 2) ? w2 : (w == 3) ? w3 : w4;
    float f = src[r];
    __bf16 h = (__bf16)f;
    __bf16 l = (__bf16)(f - (float)h);
    unsigned o = r / 576u, rem = r % 576u, ii = rem / 9u, dydx = rem % 9u;
    __bf16* wb = (__bf16*)ws;
    unsigned dst = WPB + w * 73728u + (dydx * 64u + o) * 64u + ii;
    wb[dst] = h;
    wb[dst + 36864u] = l;
}

// ---------------------------------------------------------------------------
// xt = redu_w @ x + redu_b via bf16 hi/lo split MFMA (3 products).
__global__ __launch_bounds__(256) void k_gemm_xt_mfma(const float* __restrict__ x,
                                                      const float* __restrict__ redu_b,
                                                      float* __restrict__ ws) {
    __shared__ __bf16 xhi_s[64 * 72];
    __shared__ __bf16 xlo_s[64 * 72];
    const __bf16* __restrict__ Whi = (const __bf16*)ws;
    const __bf16* __restrict__ Wlo = ((const __bf16*)ws) + WLO_BF16;
    float* xt = ws + XT_OFF;
    const int n = blockIdx.y;
    const int d0 = blockIdx.x * 256;
    const int tid = threadIdx.x;
    const int wave = tid >> 6, lane = tid & 63;
    const int lrow = lane & 15, lkg = lane >> 4;
    const int m_base = d0 + wave * 64;
    const float* __restrict__ xn = x + n * 98304;
    const int s4 = tid & 15, cb = tid >> 4;

    v4f acc[4][4];
#pragma unroll
    for (int mt = 0; mt < 4; ++mt)
#pragma unroll
        for (int nt = 0; nt < 4; ++nt) acc[mt][nt] = (v4f){0.f, 0.f, 0.f, 0.f};

    for (int c0 = 0; c0 < 1536; c0 += 64) {
        float4 v[4];
#pragma unroll
        for (int j = 0; j < 4; ++j)
            v[j] = *(const float4*)&xn[(c0 + cb * 4 + j) * 64 + s4 * 4];
        __syncthreads();
#pragma unroll
        for (int i = 0; i < 4; ++i) {
            v4bf hv, lv;
#pragma unroll
            for (int j = 0; j < 4; ++j) {
                float f = ((const float*)&v[j])[i];
                __bf16 h = (__bf16)f;
                hv[j] = h;
                lv[j] = (__bf16)(f - (float)h);
            }
            int row = s4 * 4 + i;
            *(v4bf*)&xhi_s[row * 72 + cb * 4] = hv;
            *(v4bf*)&xlo_s[row * 72 + cb * 4] = lv;
        }
        __syncthreads();
#pragma unroll
        for (int ks = 0; ks < 64; ks += 32) {
            v8bf bh[4], bl[4], ah[4], al[4];
#pragma unroll
            for (int nt = 0; nt < 4; ++nt) {
                int off = (nt * 16 + lrow) * 72 + ks + lkg * 8;
                bh[nt] = *(const v8bf*)&xhi_s[off];
                bl[nt] = *(const v8bf*)&xlo_s[off];
            }
#pragma unroll
            for (int mt = 0; mt < 4; ++mt) {
                int gi = (m_base + mt * 16 + lrow) * 1536 + c0 + ks + lkg * 8;
                ah[mt] = *(const v8bf*)&Whi[gi];
                al[mt] = *(const v8bf*)&Wlo[gi];
            }
#pragma unroll
            for (int mt = 0; mt < 4; ++mt)
#pragma unroll
                for (int nt = 0; nt < 4; ++nt) {
                    acc[mt][nt] = __builtin_amdgcn_mfma_f32_16x16x32_bf16(
                        ah[mt], bh[nt], acc[mt][nt], 0, 0, 0);
                    acc[mt][nt] = __builtin_amdgcn_mfma_f32_16x16x32_bf16(
                        ah[mt], bl[nt], acc[mt][nt], 0, 0, 0);
                    acc[mt][nt] = __builtin_amdgcn_mfma_f32_16x16x32_bf16(
                        al[mt], bh[nt], acc[mt][nt], 0, 0, 0);
                }
        }
    }
#pragma unroll
    for (int mt = 0; mt < 4; ++mt) {
#pragma unroll
        for (int r = 0; r < 4; ++r) {
            int m = m_base + mt * 16 + lkg * 4 + r;
            float bias = redu_b[m];
#pragma unroll
            for (int nt = 0; nt < 4; ++nt) {
                int s = nt * 16 + lrow;
                xt[(n * 512 + m) * 64 + s] = acc[mt][nt][r] + bias;
            }
        }
    }
}

// ---------------------------------------------------------------------------
// wxpb = w_x @ xt ; per n: (64x512)@(512x64). grid 256, block 256, 4x4/thread.
__global__ __launch_bounds__(256) void k_gemm_wxpb(float* __restrict__ ws) {
    __shared__ float Aw[16 * 64];
    __shared__ float Bx[16 * 64];
    const float* wxT = ws + WXT_OFF;
    const float* xt = ws + XT_OFF;
    float* wxpb = ws + WXPB_OFF;
    const int n = blockIdx.x;
    const int tid = threadIdx.x;
    const int sg = tid & 15, kg = tid >> 4;

    float acc[4][4];
#pragma unroll
    for (int i = 0; i < 4; ++i)
#pragma unroll
        for (int j = 0; j < 4; ++j) acc[i][j] = 0.f;

    for (int d0 = 0; d0 < 512; d0 += 16) {
        int cc = tid >> 4, q = tid & 15;
        *(float4*)&Aw[cc * 64 + q * 4] = *(const float4*)&wxT[(d0 + cc) * 64 + q * 4];
        *(float4*)&Bx[cc * 64 + q * 4] = *(const float4*)&xt[n * 32768 + (d0 + cc) * 64 + q * 4];
        __syncthreads();
#pragma unroll
        for (int c2 = 0; c2 < 16; ++c2) {
            float4 a = *(const float4*)&Aw[c2 * 64 + kg * 4];
            float4 b = *(const float4*)&Bx[c2 * 64 + sg * 4];
            float av[4] = {a.x, a.y, a.z, a.w};
            float bv[4] = {b.x, b.y, b.z, b.w};
#pragma unroll
            for (int i = 0; i < 4; ++i)
#pragma unroll
                for (int j = 0; j < 4; ++j)
                    acc[i][j] = fmaf(av[i], bv[j], acc[i][j]);
        }
        __syncthreads();
    }
#pragma unroll
    for (int i = 0; i < 4; ++i) {
        float4 o = {acc[i][0], acc[i][1], acc[i][2], acc[i][3]};
        *(float4*)&wxpb[(n * 64 + kg * 4 + i) * 64 + sg * 4] = o;
    }
}

// ---------------------------------------------------------------------------
// generic 3x3 conv (fp32), used only for attv (256 parallel images).
__global__ __launch_bounds__(128) void k_conv3x3(const float* __restrict__ in,
                                                 const float* __restrict__ wt,
                                                 const float* __restrict__ bias,
                                                 float* __restrict__ out) {
    __shared__ float in_s[4096];
    __shared__ float w_s[16 * 576];
    const int img = blockIdx.y;
    const int k0 = blockIdx.x * 16;
    const int tid = threadIdx.x;
    const int kl = tid >> 3, y = tid & 7;
#pragma unroll
    for (int i = 0; i < 8; ++i) {
        int f = tid + i * 128;
        *(float4*)&in_s[f * 4] = *(const float4*)&in[img * 4096 + f * 4];
    }
#pragma unroll
    for (int i = 0; i < 18; ++i) {
        int f = tid + i * 128;
        *(float4*)&w_s[f * 4] = *(const float4*)&wt[k0 * 576 + f * 4];
    }
    __syncthreads();
    float o[8];
#pragma unroll
    for (int xx = 0; xx < 8; ++xx) o[xx] = 0.f;
    for (int kp = 0; kp < 64; ++kp) {
        const float* wp = &w_s[kl * 576 + kp * 9];
        float wv[9];
#pragma unroll
        for (int q = 0; q < 9; ++q) wv[q] = wp[q];
#pragma unroll
        for (int dy = 0; dy < 3; ++dy) {
            int yy = y + dy - 1;
            if (yy >= 0 && yy < 8) {
                float4 ra = *(const float4*)&in_s[kp * 64 + yy * 8];
                float4 rb = *(const float4*)&in_s[kp * 64 + yy * 8 + 4];
                float r[8] = {ra.x, ra.y, ra.z, ra.w, rb.x, rb.y, rb.z, rb.w};
                float wa = wv[dy * 3 + 0], wb = wv[dy * 3 + 1], wc = wv[dy * 3 + 2];
#pragma unroll
                for (int xx = 0; xx < 8; ++xx) {
                    float t = wb * r[xx];
                    if (xx > 0) t += wa * r[xx - 1];
                    if (xx < 7) t += wc * r[xx + 1];
                    o[xx] += t;
                }
            }
        }
    }
    float bv = bias ? bias[k0 + kl] : 0.f;
    float4 o0 = {o[0] + bv, o[1] + bv, o[2] + bv, o[3] + bv};
    float4 o1 = {o[4] + bv, o[5] + bv, o[6] + bv, o[7] + bv};
    *(float4*)&out[img * 4096 + (k0 + kl) * 64 + y * 8] = o0;
    *(float4*)&out[img * 4096 + (k0 + kl) * 64 + y * 8 + 4] = o1;
}

// ---------------------------------------------------------------------------
// R8: 4-wave conv. Each wave owns rows mt*16..mt*16+15 and ALL 64 output
// columns (4 col-groups, acc[4]). Single-bf16 weights (R4). All 18 weight
// fragments batched up front (72 VGPRs in flight) — legal under the 256-VGPR
// envelope that a 256-thread block earns from the allocator's fixed
// 2-blocks/CU target (512thr->128, 1024thr->64 measured; 256thr->256).
__device__ __forceinline__ void conv_mfma(const __bf16* __restrict__ Wh,
                                          const __bf16* tS,
                                          int l15, int kg8, int mt, v4f acc[4]) {
    v8bf vz;
#pragma unroll
    for (int q = 0; q < 8; ++q) vz[q] = (__bf16)0.f;
#pragma unroll
    for (int i = 0; i < 4; ++i) acc[i] = (v4f){0.f, 0.f, 0.f, 0.f};
    const int yb = l15 >> 3, xb = l15 & 7;
    v8bf wh[9][2];
#pragma unroll
    for (int p = 0; p < 9; ++p) {
        const int wrow = (p * 64 + mt * 16 + l15) * 64 + kg8;
#pragma unroll
        for (int kci = 0; kci < 2; ++kci)
            wh[p][kci] = *(const v8bf*)&Wh[wrow + kci * 32];
    }
#pragma unroll
    for (int dy = 0; dy < 3; ++dy)
#pragma unroll
        for (int dx = 0; dx < 3; ++dx) {
            const int x0 = xb + dx - 1;
            const bool okx = (unsigned)x0 < 8u;
#pragma unroll
            for (int i = 0; i < 4; ++i) {
                const int y0 = yb + dy - 1 + 2 * i;
                const bool ok = ((unsigned)y0 < 8u) & okx;
                const int s0 = ((y0 * 8 + x0) & 63) * 72 + kg8;
#pragma unroll
                for (int kci = 0; kci < 2; ++kci) {
                    v8bf b = ok ? *(const v8bf*)&tS[s0 + kci * 32] : vz;
                    acc[i] = __builtin_amdgcn_mfma_f32_16x16x32_bf16(
                        wh[dy * 3 + dx][kci], b, acc[i], 0, 0, 0);
                }
            }
        }
}

// Fused triple conv over the same tA (ah/Uz/Ur): per-dy weight batch
// (18 fragments = 72 VGPRs) + shared B reads. Peak live ~150 regs < 256.
__device__ __forceinline__ void conv_mfma3(const __bf16* __restrict__ W0,
                                           const __bf16* __restrict__ W1,
                                           const __bf16* __restrict__ W2,
                                           const __bf16* tS,
                                           int l15, int kg8, int mt,
                                           v4f a0[4], v4f a1[4], v4f a2[4]) {
    v8bf vz;
#pragma unroll
    for (int q = 0; q < 8; ++q) vz[q] = (__bf16)0.f;
#pragma unroll
    for (int i = 0; i < 4; ++i) {
        a0[i] = (v4f){0.f, 0.f, 0.f, 0.f};
        a1[i] = (v4f){0.f, 0.f, 0.f, 0.f};
        a2[i] = (v4f){0.f, 0.f, 0.f, 0.f};
    }
    const int yb = l15 >> 3, xb = l15 & 7;
#pragma unroll
    for (int dy = 0; dy < 3; ++dy) {
        v8bf w0[3][2], w1[3][2], w2[3][2];
#pragma unroll
        for (int dx = 0; dx < 3; ++dx) {
            const int wrow = ((dy * 3 + dx) * 64 + mt * 16 + l15) * 64 + kg8;
#pragma unroll
            for (int kci = 0; kci < 2; ++kci) {
                w0[dx][kci] = *(const v8bf*)&W0[wrow + kci * 32];
                w1[dx][kci] = *(const v8bf*)&W1[wrow + kci * 32];
                w2[dx][kci] = *(const v8bf*)&W2[wrow + kci * 32];
            }
        }
#pragma unroll
        for (int dx = 0; dx < 3; ++dx) {
            const int x0 = xb + dx - 1;
            const bool okx = (unsigned)x0 < 8u;
#pragma unroll
            for (int i = 0; i < 4; ++i) {
                const int y0 = yb + dy - 1 + 2 * i;
                const bool ok = ((unsigned)y0 < 8u) & okx;
                const int s0 = ((y0 * 8 + x0) & 63) * 72 + kg8;
#pragma unroll
                for (int kci = 0; kci < 2; ++kci) {
                    v8bf b = ok ? *(const v8bf*)&tS[s0 + kci * 32] : vz;
                    a0[i] = __builtin_amdgcn_mfma_f32_16x16x32_bf16(w0[dx][kci], b, a0[i], 0, 0, 0);
                    a1[i] = __builtin_amdgcn_mfma_f32_16x16x32_bf16(w1[dx][kci], b, a1[i], 0, 0, 0);
                    a2[i] = __builtin_amdgcn_mfma_f32_16x16x32_bf16(w2[dx][kci], b, a2[i], 0, 0, 0);
                }
            }
        }
    }
}

// ---------------------------------------------------------------------------
// Whole recurrence in one kernel: grid 32 (one block per b), 256 threads.
// R8: 4 waves. 512-wide phases run as rep-2 loops (vtid = tid + rep*256).
// Rationale: allocator targets 2 blocks/CU regardless of LDS or attributes
// (measured: 512thr->128 VGPR, 1024thr->64). A 256-thr block gets a 256-VGPR
// envelope: the 14-phase serial chain can finally batch loads deeply and
// keep cross-phase state (az/ar) without spilling. Costs 1 wave/SIMD of
// overlap — the bet is that fewer, wider latency exposures win.
// One wave per output row => asum reduce needs no LDS atomics.
__global__ __launch_bounds__(256) void k_recur(const float* __restrict__ att_b,
                                               const float* __restrict__ share_b,
                                               const float* __restrict__ fc1_w,
                                               const float* __restrict__ fc2_w,
                                               float* __restrict__ ws) {
    __shared__ float h_s[4096];                                   // h [k][s]
    __shared__ __attribute__((aligned(16))) __bf16 tA[64 * 72];   // T(in) [s][kp]
    __shared__ float cA[64 * 65];                                 // conv out / scratch
    __shared__ float cB[64 * 65];
    __shared__ float misc[1088];  // em|exs [0..511], ex|als [512..1023], h1|asum [1024..]
    __shared__ __attribute__((aligned(16))) _Float16 attv_s[32768];  // [tp][k][s] fp16
    const int b = blockIdx.x, tid = threadIdx.x;
    const int lane = tid & 63;
    const int wave = tid >> 6;            // 0..3
    const int mt = wave;
    const int l15 = lane & 15, kg = lane >> 4, kg8 = kg * 8;
    const __bf16* Wp = (const __bf16*)ws + WPB;
    const float* attv = ws + ATTV_OFF;
    const float* wxpb = ws + WXPB_OFF;
    float* hsg = ws + HS_OFF;
    float* asg = ws + ASUM_OFF;

    // ---- one-time: stage attv (this b) into LDS as fp16
    {
        const float* src = attv + b * 32768;
        for (int i = tid; i < 8192; i += 256) {
            float4 v = *(const float4*)&src[i * 4];
            v4h h4 = {(_Float16)v.x, (_Float16)v.y, (_Float16)v.z, (_Float16)v.w};
            *(v4h*)&attv_s[i * 4] = h4;
        }
    }

    for (int i = tid; i < 4096; i += 256) h_s[i] = 0.f;
    float abvr[2];
#pragma unroll
    for (int rep = 0; rep < 2; ++rep) abvr[rep] = att_b[(tid + rep * 256) >> 3];
    float sb4[4];
#pragma unroll
    for (int r = 0; r < 4; ++r) sb4[r] = share_b[mt * 16 + kg * 4 + r];
    __syncthreads();

    for (int t = 0; t < 8; ++t) {
        // ---- tA = T(h)
#pragma unroll
        for (int rep = 0; rep < 2; ++rep) {
            int s = tid & 63, g = (tid >> 6) + rep * 4;
#pragma unroll
            for (int q4 = 0; q4 < 2; ++q4) {
                v4bf hv;
#pragma unroll
                for (int q = 0; q < 4; ++q) hv[q] = (__bf16)h_s[(g * 8 + q4 * 4 + q) * 64 + s];
                *(v4bf*)&tA[s * 72 + g * 8 + q4 * 4] = hv;
            }
        }
        __syncthreads();
        // ---- fused ah/Uz/Ur convs: ah -> cA; az, ar stay in registers
        v4f az[4], ar[4];
        {
            v4f a[4];
            conv_mfma3(Wp, Wp + 2u * 73728u, Wp + 3u * 73728u, tA,
                       l15, kg8, mt, a, az, ar);
#pragma unroll
            for (int i = 0; i < 4; ++i)
#pragma unroll
                for (int r = 0; r < 4; ++r)
                    cA[(mt * 16 + kg * 4 + r) * 65 + i * 16 + l15] = a[i][r];
        }
        __syncthreads();
        // ---- e = relu(attv+ah); mean/max over s -> em/ex  (attv from LDS fp16)
#pragma unroll
        for (int rep = 0; rep < 2; ++rep) {
            int vt = tid + rep * 256;
            int kk = vt >> 3, yy = vt & 7;
            float ah8[8];
            const float* cr = &cA[kk * 65 + yy * 8];
#pragma unroll
            for (int xx = 0; xx < 8; ++xx) ah8[xx] = cr[xx] + abvr[rep];
            for (int tp = 0; tp < 8; ++tp) {
                v8h va = *(const v8h*)&attv_s[tp * 4096 + kk * 64 + yy * 8];
                float s_ = 0.f, m_ = 0.f;
#pragma unroll
                for (int xx = 0; xx < 8; ++xx) {
                    float v = fmaxf((float)va[xx] + ah8[xx], 0.f);
                    s_ += v;
                    m_ = fmaxf(m_, v);
                }
                s_ += __shfl_down(s_, 4, 8);
                s_ += __shfl_down(s_, 2, 8);
                s_ += __shfl_down(s_, 1, 8);
                m_ = fmaxf(m_, __shfl_down(m_, 4, 8));
                m_ = fmaxf(m_, __shfl_down(m_, 2, 8));
                m_ = fmaxf(m_, __shfl_down(m_, 1, 8));
                if (yy == 0) {
                    misc[tp * 64 + kk] = s_ * (1.f / 64.f);
                    misc[512 + tp * 64 + kk] = m_;
                }
            }
        }
        __syncthreads();
        // ---- fc1: 64 outputs x 4 partials (256 thr), float4 loads
        {
            int i2 = tid >> 2, part = tid & 3;
            int i = i2 & 31;
            const float* src = misc + ((i2 < 32) ? 0 : 512);
            const float* wrow = fc1_w + i * 512 + part * 128;
            const float* s2 = src + part * 128;
            float p = 0.f;
#pragma unroll
            for (int c4 = 0; c4 < 32; ++c4) {
                float4 wv = *(const float4*)&wrow[c4 * 4];
                float4 sv = *(const float4*)&s2[c4 * 4];
                p = fmaf(wv.x, sv.x, p);
                p = fmaf(wv.y, sv.y, p);
                p = fmaf(wv.z, sv.z, p);
                p = fmaf(wv.w, sv.w, p);
            }
            p += __shfl_down(p, 2, 4);
            p += __shfl_down(p, 1, 4);
            if (part == 0) misc[1024 + i2] = fmaxf(p, 0.f);
        }
        __syncthreads();
        // ---- fc2 + tanh + exp -> exs at misc[0..511], float4 loads
#pragma unroll
        for (int rep = 0; rep < 2; ++rep) {
            int vt = tid + rep * 256;
            const float* w2 = fc2_w + vt * 32;
            float gm = 0.f, gx = 0.f;
#pragma unroll
            for (int i4 = 0; i4 < 8; ++i4) {
                float4 wv = *(const float4*)&w2[i4 * 4];
                gm = fmaf(wv.x, misc[1024 + i4 * 4 + 0], gm);
                gm = fmaf(wv.y, misc[1024 + i4 * 4 + 1], gm);
                gm = fmaf(wv.z, misc[1024 + i4 * 4 + 2], gm);
                gm = fmaf(wv.w, misc[1024 + i4 * 4 + 3], gm);
                gx = fmaf(wv.x, misc[1056 + i4 * 4 + 0], gx);
                gx = fmaf(wv.y, misc[1056 + i4 * 4 + 1], gx);
                gx = fmaf(wv.z, misc[1056 + i4 * 4 + 2], gx);
                gx = fmaf(wv.w, misc[1056 + i4 * 4 + 3], gx);
            }
            misc[vt] = expf(tanhf(gm + gx));
        }
        __syncthreads();
        // ---- softmax over T -> als at misc[512..1023]
#pragma unroll
        for (int rep = 0; rep < 2; ++rep) {
            int vt = tid + rep * 256;
            int k6 = vt & 63;
            float den = 0.f;
#pragma unroll
            for (int tp = 0; tp < 8; ++tp) den += misc[tp * 64 + k6];
            den += (den == 0.f) ? 1.f : 0.f;
            misc[512 + vt] = misc[vt] / den;
        }
        __syncthreads();
        // ---- wxtp: read wxpb from global (L2-resident), weighted by als;
        //      then tA = T(wxtp)
#pragma unroll
        for (int rep = 0; rep < 2; ++rep) {
            int vt = tid + rep * 256;
            int kk = vt >> 3, yy = vt & 7;
            float wx8[8];
#pragma unroll
            for (int xx = 0; xx < 8; ++xx) wx8[xx] = 0.f;
            const float* src0 = wxpb + b * 32768 + kk * 64 + yy * 8;
#pragma unroll
            for (int tp = 0; tp < 8; ++tp) {
                float al = misc[512 + tp * 64 + kk];
                float4 v0 = *(const float4*)&src0[tp * 4096];
                float4 v1 = *(const float4*)&src0[tp * 4096 + 4];
                float v[8] = {v0.x, v0.y, v0.z, v0.w, v1.x, v1.y, v1.z, v1.w};
#pragma unroll
                for (int xx = 0; xx < 8; ++xx) wx8[xx] = fmaf(al, v[xx], wx8[xx]);
            }
#pragma unroll
            for (int xx = 0; xx < 8; ++xx) tA[(yy * 8 + xx) * 72 + kk] = (__bf16)wx8[xx];
        }
        __syncthreads();
        // ---- share conv
        v4f ash[4];
        conv_mfma(Wp + 1u * 73728u, tA, l15, kg8, mt, ash);
        // ---- gates (frag domain); rh -> cB
        float zf[4][4], wof[4][4];
#pragma unroll
        for (int i = 0; i < 4; ++i)
#pragma unroll
            for (int r = 0; r < 4; ++r) {
                int ko = mt * 16 + kg * 4 + r;
                int s = i * 16 + l15;
                float wo = ash[i][r] + sb4[r];
                float z = 1.f / (1.f + expf(-(wo + az[i][r])));
                float rr = 1.f / (1.f + expf(-(wo + ar[i][r])));
                cB[ko * 65 + s] = rr * h_s[ko * 64 + s];
                zf[i][r] = z;
                wof[i][r] = wo;
            }
        __syncthreads();
        // ---- tA = T(rh)
#pragma unroll
        for (int rep = 0; rep < 2; ++rep) {
            int s = tid & 63, g = (tid >> 6) + rep * 4;
#pragma unroll
            for (int q4 = 0; q4 < 2; ++q4) {
                v4bf hv;
#pragma unroll
                for (int q = 0; q < 4; ++q) hv[q] = (__bf16)cB[(g * 8 + q4 * 4 + q) * 65 + s];
                *(v4bf*)&tA[s * 72 + g * 8 + q4 * 4] = hv;
            }
        }
        __syncthreads();
        // ---- Uh conv + final update (one wave per row: direct asum store)
        {
            v4f ach[4];
            conv_mfma(Wp + 4u * 73728u, tA, l15, kg8, mt, ach);
#pragma unroll
            for (int r = 0; r < 4; ++r) {
                int ko = mt * 16 + kg * 4 + r;
                float rsum = 0.f;
#pragma unroll
                for (int i = 0; i < 4; ++i) {
                    int s = i * 16 + l15;
                    float hh = tanhf(wof[i][r] + ach[i][r]);
                    float hold = h_s[ko * 64 + s];
                    float hn = (1.f - zf[i][r]) * hh + zf[i][r] * hold;
                    h_s[ko * 64 + s] = hn;
                    hsg[((t * 32 + b) * 64 + ko) * 64 + s] = hn;
                    rsum += hn;
                }
                rsum += __shfl_xor(rsum, 8, 16);
                rsum += __shfl_xor(rsum, 4, 16);
                rsum += __shfl_xor(rsum, 2, 16);
                rsum += __shfl_xor(rsum, 1, 16);
                if (l15 == 0) misc[1024 + ko] = rsum;
            }
        }
        __syncthreads();
        if (tid < 64) asg[b * 512 + t * 64 + tid] = misc[1024 + tid];
        __syncthreads();
    }
}

// ---------------------------------------------------------------------------
// VLAD: V[b,k,d] = sum_{t,hw} hs*xt - (sum_t asum)*centers. grid (8,32), 256 thr
__global__ __launch_bounds__(256) void k_vlad(const float* __restrict__ centers,
                                              const float* __restrict__ ws,
                                              float* __restrict__ out) {
    __shared__ float As[16 * 68];
    __shared__ float Bs[16 * 68];
    const int b = blockIdx.y;
    const int d0 = blockIdx.x * 64;
    const int tid = threadIdx.x;
    const int kq = tid & 15, dq = tid >> 4;
    const int lk = tid >> 2, q = tid & 3;
    const float* hs = ws + HS_OFF;
    const float* xt = ws + XT_OFF;
    float acc[4][4];
#pragma unroll
    for (int i = 0; i < 4; ++i)
#pragma unroll
        for (int j = 0; j < 4; ++j) acc[i][j] = 0.f;

    for (int rc = 0; rc < 512; rc += 16) {
        int t = rc >> 6, hw0 = rc & 63;
        float4 va = *(const float4*)&hs[((t * 32 + b) * 64 + lk) * 64 + hw0 + q * 4];
        float4 vb = *(const float4*)&xt[(b * 8 + t) * 32768 + (d0 + lk) * 64 + hw0 + q * 4];
        __syncthreads();
        As[(q * 4 + 0) * 68 + lk] = va.x;
        As[(q * 4 + 1) * 68 + lk] = va.y;
        As[(q * 4 + 2) * 68 + lk] = va.z;
        As[(q * 4 + 3) * 68 + lk] = va.w;
        Bs[(q * 4 + 0) * 68 + lk] = vb.x;
        Bs[(q * 4 + 1) * 68 + lk] = vb.y;
        Bs[(q * 4 + 2) * 68 + lk] = vb.z;
        Bs[(q * 4 + 3) * 68 + lk] = vb.w;
        __syncthreads();
#pragma unroll
        for (int cc = 0; cc < 16; ++cc) {
            float4 a = *(const float4*)&As[cc * 68 + kq * 4];
            float4 bb = *(const float4*)&Bs[cc * 68 + dq * 4];
            float av[4] = {a.x, a.y, a.z, a.w};
            float bv[4] = {bb.x, bb.y, bb.z, bb.w};
#pragma unroll
            for (int i = 0; i < 4; ++i)
#pragma unroll
                for (int j = 0; j < 4; ++j)
                    acc[i][j] = fmaf(av[i], bv[j], acc[i][j]);
        }
    }
    const float* asum = ws + ASUM_OFF;
#pragma unroll
    for (int i = 0; i < 4; ++i) {
        int k = kq * 4 + i;
        float at = 0.f;
#pragma unroll
        for (int tp = 0; tp < 8; ++tp) at += asum[b * 512 + tp * 64 + k];
        float4 cen = *(const float4*)&centers[k * 512 + d0 + dq * 4];
        float4 o = {acc[i][0] - at * cen.x, acc[i][1] - at * cen.y,
                    acc[i][2] - at * cen.z, acc[i][3] - at * cen.w};
        *(float4*)&out[b * 32768 + k * 512 + d0 + dq * 4] = o;
    }
}

// ---------------------------------------------------------------------------
__global__ __launch_bounds__(64) void k_norm1(float* __restrict__ out) {
    const int b = blockIdx.x >> 6, k = blockIdx.x & 63;
    float* p = out + b * 32768 + k * 512;
    const int tid = threadIdx.x;
    float v[8];
    float ss = 0.f;
#pragma unroll
    for (int i = 0; i < 8; ++i) {
        v[i] = p[tid + i * 64];
        ss = fmaf(v[i], v[i], ss);
    }
#pragma unroll
    for (int off = 32; off > 0; off >>= 1) ss += __shfl_down(ss, off, 64);
    ss = __shfl(ss, 0, 64);
    float sc = 1.f / fmaxf(sqrtf(ss), 1e-12f);
#pragma unroll
    for (int i = 0; i < 8; ++i) p[tid + i * 64] = v[i] * sc;
}

__global__ __launch_bounds__(256) void k_norm2(float* __restrict__ out) {
    __shared__ float red[4];
    __shared__ float stot;
    const int b = blockIdx.x;
    const int tid = threadIdx.x;
    float* p = out + b * 32768;
    float ss = 0.f;
    for (int i = 0; i < 32; ++i) {
        float4 v = *(const float4*)&p[tid * 4 + i * 1024];
        ss += v.x * v.x + v.y * v.y + v.z * v.z + v.w * v.w;
    }
#pragma unroll
    for (int off = 32; off > 0; off >>= 1) ss += __shfl_down(ss, off, 64);
    if ((tid & 63) == 0) red[tid >> 6] = ss;
    __syncthreads();
    if (tid == 0) stot = 1.f / fmaxf(sqrtf(red[0] + red[1] + red[2] + red[3]), 1e-12f);
    __syncthreads();
    float sc = stot;
    for (int i = 0; i < 32; ++i) {
        float4 v = *(const float4*)&p[tid * 4 + i * 1024];
        v.x *= sc; v.y *= sc; v.z *= sc; v.w *= sc;
        *(float4*)&p[tid * 4 + i * 1024] = v;
    }
}

// ---------------------------------------------------------------------------
extern "C" void kernel_launch(void* const* d_in, const int* in_sizes, int n_in,
                              void* d_out, int out_size, void* d_ws, size_t ws_size,
                              hipStream_t stream) {
    const float* x       = (const float*)d_in[0];
    const float* redu_w  = (const float*)d_in[1];
    const float* redu_b  = (const float*)d_in[2];
    const float* w_x     = (const float*)d_in[3];
    const float* att_x   = (const float*)d_in[4];
    const float* att_h_w = (const float*)d_in[5];
    const float* att_b   = (const float*)d_in[6];
    const float* share_w = (const float*)d_in[7];
    const float* share_b = (const float*)d_in[8];
    const float* U_r     = (const float*)d_in[9];
    const float* U_z     = (const float*)d_in[10];
    const float* U_h     = (const float*)d_in[11];
    const float* centers = (const float*)d_in[12];
    const float* fc1_w   = (const float*)d_in[13];
    const float* fc2_w   = (const float*)d_in[14];
    float* ws = (float*)d_ws;
    float* out = (float*)d_out;

    k_prep<<<dim3(3200), dim3(256), 0, stream>>>(redu_w, w_x, ws);
    k_prep_w<<<dim3(720), dim3(256), 0, stream>>>(att_h_w, share_w, U_z, U_r, U_h, ws);
    k_gemm_xt_mfma<<<dim3(2, 256), dim3(256), 0, stream>>>(x, redu_b, ws);
    k_gemm_wxpb<<<dim3(256), dim3(256), 0, stream>>>(ws);
    k_conv3x3<<<dim3(4, 256), dim3(128), 0, stream>>>(ws + WXPB_OFF, att_x,
                                                      (const float*)nullptr, ws + ATTV_OFF);
    k_recur<<<dim3(32), dim3(256), 0, stream>>>(att_b, share_b, fc1_w, fc2_w, ws);
    k_vlad<<<dim3(8, 32), dim3(256), 0, stream>>>(centers, ws, out);
    k_norm1<<<dim3(2048), dim3(64), 0, stream>>>(out);
    k_norm2<<<dim3(32), dim3(256), 0, stream>>>(out);
}

// Round 11
// 697.832 us; speedup vs baseline: 1.6049x; 1.0571x over previous
//
#include <hip/hip_runtime.h>
#include <math.h>

// Problem constants
#define T_   8
#define K_   64
#define D_   512
#define CIN_ 1536
#define B_   32
#define S_   64    // H*W = 8*8
#define NT_  256   // B*T

// Workspace layout (float offsets)
#define WLO_BF16  786432u     // bf16-element offset of Wlo within bf16 view
#define WXT_OFF   786432u     // [512][64]  transposed w_x (float offset)
#define XT_OFF    819200u     // [256][512][64]
#define WXPB_OFF  9207808u    // [256][64][64]
#define ATTV_OFF  10256384u   // region reused in R10 for the att_x weight pack
#define HS_OFF    11436032u   // [8][32][64][64]
#define ASUM_OFF  13041664u   // [32][8][64]
// conv-weight pack (bf16 elements): 5 weights x (hi 36864 + lo 36864),
// layout per weight: [dydx(9)][o(64)][i(64)]. Only hi halves are read (R4).
// Slots: 0=att_h_w 1=share_w 2=U_z 3=U_r 4=U_h.
#define WPB       25034752u
// R10: att_x hi pack lives in the (otherwise unused since R9) ATTV region.
// R9's placement at WPB+5*73728 extended the bf16 pack ~147 KB past the
// footprint every prior passing build used — workspace OOB writes are the
// prime suspect for the two container deaths. This placement is strictly
// within the region R0-R8 demonstrably owned (attv floats lived here).
#define WATTX_BF16 20512768u  // = 2 * ATTV_OFF (bf16-element offset)

typedef __bf16 v8bf __attribute__((ext_vector_type(8)));
typedef __bf16 v4bf __attribute__((ext_vector_type(4)));
typedef float  v4f  __attribute__((ext_vector_type(4)));
typedef _Float16 v4h __attribute__((ext_vector_type(4)));
typedef _Float16 v8h __attribute__((ext_vector_type(8)));

// ---------------------------------------------------------------------------
// prep: split redu_w -> bf16 hi/lo, transpose w_x -> wxT[d][k]
__global__ __launch_bounds__(256) void k_prep(const float* __restrict__ redu_w,
                                              const float* __restrict__ w_x,
                                              float* __restrict__ ws) {
    unsigned idx = blockIdx.x * 256u + threadIdx.x;
    if (idx < 786432u) {
        float f = redu_w[idx];
        __bf16 h = (__bf16)f;
        __bf16 l = (__bf16)(f - (float)h);
        __bf16* wb = (__bf16*)ws;
        wb[idx] = h;
        wb[WLO_BF16 + idx] = l;
    } else if (idx < 819200u) {
        unsigned i = idx - 786432u;
        unsigned dd = i >> 6, k = i & 63u;
        ws[WXT_OFF + i] = w_x[k * 512u + dd];
    }
}

// ---------------------------------------------------------------------------
// prep conv weights: [o][i][ky][kx] fp32 -> bf16 hi/lo [dydx][o][i].
// Slots 0..4 exactly as in the known-good R8 build; slot 5 (att_x) goes
// hi-only into the ATTV region (WATTX_BF16).
__global__ __launch_bounds__(256) void k_prep_w(const float* __restrict__ w0,
                                                const float* __restrict__ w1,
                                                const float* __restrict__ w2,
                                                const float* __restrict__ w3,
                                                const float* __restrict__ w4,
                                                const float* __restrict__ w5,
                                                float* __restrict__ ws) {
    unsigned idx = blockIdx.x * 256u + threadIdx.x;
    if (idx >= 221184u) return;
    unsigned w = idx / 36864u, r = idx % 36864u;
    const float* src = (w == 0) ? w0 : (w == 1) ? w1 : (w == 2) ? w2
                     : (w == 3) ? w3 : (w == 4) ? w4 : w5;
    float f = src[r];
    __bf16 h = (__bf16)f;
    __bf16 l = (__bf16)(f - (float)h);
    unsigned o = r / 576u, rem = r % 576u, ii = rem / 9u, dydx = rem % 9u;
    __bf16* wb = (__bf16*)ws;
    if (w < 5u) {
        unsigned dst = WPB + w * 73728u + (dydx * 64u + o) * 64u + ii;
        wb[dst] = h;
        wb[dst + 36864u] = l;
    } else {
        wb[WATTX_BF16 + (dydx * 64u + o) * 64u + ii] = h;   // hi only
    }
}

// ---------------------------------------------------------------------------
// xt = redu_w @ x + redu_b via bf16 hi/lo split MFMA (3 products).
__global__ __launch_bounds__(256) void k_gemm_xt_mfma(const float* __restrict__ x,
                                                      const float* __restrict__ redu_b,
                                                      float* __restrict__ ws) {
    __shared__ __bf16 xhi_s[64 * 72];
    __shared__ __bf16 xlo_s[64 * 72];
    const __bf16* __restrict__ Whi = (const __bf16*)ws;
    const __bf16* __restrict__ Wlo = ((const __bf16*)ws) + WLO_BF16;
    float* xt = ws + XT_OFF;
    const int n = blockIdx.y;
    const int d0 = blockIdx.x * 256;
    const int tid = threadIdx.x;
    const int wave = tid >> 6, lane = tid & 63;
    const int lrow = lane & 15, lkg = lane >> 4;
    const int m_base = d0 + wave * 64;
    const float* __restrict__ xn = x + n * 98304;
    const int s4 = tid & 15, cb = tid >> 4;

    v4f acc[4][4];
#pragma unroll
    for (int mt = 0; mt < 4; ++mt)
#pragma unroll
        for (int nt = 0; nt < 4; ++nt) acc[mt][nt] = (v4f){0.f, 0.f, 0.f, 0.f};

    for (int c0 = 0; c0 < 1536; c0 += 64) {
        float4 v[4];
#pragma unroll
        for (int j = 0; j < 4; ++j)
            v[j] = *(const float4*)&xn[(c0 + cb * 4 + j) * 64 + s4 * 4];
        __syncthreads();
#pragma unroll
        for (int i = 0; i < 4; ++i) {
            v4bf hv, lv;
#pragma unroll
            for (int j = 0; j < 4; ++j) {
                float f = ((const float*)&v[j])[i];
                __bf16 h = (__bf16)f;
                hv[j] = h;
                lv[j] = (__bf16)(f - (float)h);
            }
            int row = s4 * 4 + i;
            *(v4bf*)&xhi_s[row * 72 + cb * 4] = hv;
            *(v4bf*)&xlo_s[row * 72 + cb * 4] = lv;
        }
        __syncthreads();
#pragma unroll
        for (int ks = 0; ks < 64; ks += 32) {
            v8bf bh[4], bl[4], ah[4], al[4];
#pragma unroll
            for (int nt = 0; nt < 4; ++nt) {
                int off = (nt * 16 + lrow) * 72 + ks + lkg * 8;
                bh[nt] = *(const v8bf*)&xhi_s[off];
                bl[nt] = *(const v8bf*)&xlo_s[off];
            }
#pragma unroll
            for (int mt = 0; mt < 4; ++mt) {
                int gi = (m_base + mt * 16 + lrow) * 1536 + c0 + ks + lkg * 8;
                ah[mt] = *(const v8bf*)&Whi[gi];
                al[mt] = *(const v8bf*)&Wlo[gi];
            }
#pragma unroll
            for (int mt = 0; mt < 4; ++mt)
#pragma unroll
                for (int nt = 0; nt < 4; ++nt) {
                    acc[mt][nt] = __builtin_amdgcn_mfma_f32_16x16x32_bf16(
                        ah[mt], bh[nt], acc[mt][nt], 0, 0, 0);
                    acc[mt][nt] = __builtin_amdgcn_mfma_f32_16x16x32_bf16(
                        ah[mt], bl[nt], acc[mt][nt], 0, 0, 0);
                    acc[mt][nt] = __builtin_amdgcn_mfma_f32_16x16x32_bf16(
                        al[mt], bh[nt], acc[mt][nt], 0, 0, 0);
                }
        }
    }
#pragma unroll
    for (int mt = 0; mt < 4; ++mt) {
#pragma unroll
        for (int r = 0; r < 4; ++r) {
            int m = m_base + mt * 16 + lkg * 4 + r;
            float bias = redu_b[m];
#pragma unroll
            for (int nt = 0; nt < 4; ++nt) {
                int s = nt * 16 + lrow;
                xt[(n * 512 + m) * 64 + s] = acc[mt][nt][r] + bias;
            }
        }
    }
}

// ---------------------------------------------------------------------------
// wxpb = w_x @ xt ; per n: (64x512)@(512x64). grid 256, block 256, 4x4/thread.
__global__ __launch_bounds__(256) void k_gemm_wxpb(float* __restrict__ ws) {
    __shared__ float Aw[16 * 64];
    __shared__ float Bx[16 * 64];
    const float* wxT = ws + WXT_OFF;
    const float* xt = ws + XT_OFF;
    float* wxpb = ws + WXPB_OFF;
    const int n = blockIdx.x;
    const int tid = threadIdx.x;
    const int sg = tid & 15, kg = tid >> 4;

    float acc[4][4];
#pragma unroll
    for (int i = 0; i < 4; ++i)
#pragma unroll
        for (int j = 0; j < 4; ++j) acc[i][j] = 0.f;

    for (int d0 = 0; d0 < 512; d0 += 16) {
        int cc = tid >> 4, q = tid & 15;
        *(float4*)&Aw[cc * 64 + q * 4] = *(const float4*)&wxT[(d0 + cc) * 64 + q * 4];
        *(float4*)&Bx[cc * 64 + q * 4] = *(const float4*)&xt[n * 32768 + (d0 + cc) * 64 + q * 4];
        __syncthreads();
#pragma unroll
        for (int c2 = 0; c2 < 16; ++c2) {
            float4 a = *(const float4*)&Aw[c2 * 64 + kg * 4];
            float4 b = *(const float4*)&Bx[c2 * 64 + sg * 4];
            float av[4] = {a.x, a.y, a.z, a.w};
            float bv[4] = {b.x, b.y, b.z, b.w};
#pragma unroll
            for (int i = 0; i < 4; ++i)
#pragma unroll
                for (int j = 0; j < 4; ++j)
                    acc[i][j] = fmaf(av[i], bv[j], acc[i][j]);
        }
        __syncthreads();
    }
#pragma unroll
    for (int i = 0; i < 4; ++i) {
        float4 o = {acc[i][0], acc[i][1], acc[i][2], acc[i][3]};
        *(float4*)&wxpb[(n * 64 + kg * 4 + i) * 64 + sg * 4] = o;
    }
}

// ---------------------------------------------------------------------------
// R8 conv: 4 waves, each wave owns rows mt*16..+15, all 64 cols (acc[4]).
// Single-bf16 weights; all 18 weight fragments batched (256-VGPR envelope
// from the 2-blocks/CU allocator law: 256thr -> 256 VGPR, measured R8).
__device__ __forceinline__ void conv_mfma(const __bf16* __restrict__ Wh,
                                          const __bf16* tS,
                                          int l15, int kg8, int mt, v4f acc[4]) {
    v8bf vz;
#pragma unroll
    for (int q = 0; q < 8; ++q) vz[q] = (__bf16)0.f;
#pragma unroll
    for (int i = 0; i < 4; ++i) acc[i] = (v4f){0.f, 0.f, 0.f, 0.f};
    const int yb = l15 >> 3, xb = l15 & 7;
    v8bf wh[9][2];
#pragma unroll
    for (int p = 0; p < 9; ++p) {
        const int wrow = (p * 64 + mt * 16 + l15) * 64 + kg8;
#pragma unroll
        for (int kci = 0; kci < 2; ++kci)
            wh[p][kci] = *(const v8bf*)&Wh[wrow + kci * 32];
    }
#pragma unroll
    for (int dy = 0; dy < 3; ++dy)
#pragma unroll
        for (int dx = 0; dx < 3; ++dx) {
            const int x0 = xb + dx - 1;
            const bool okx = (unsigned)x0 < 8u;
#pragma unroll
            for (int i = 0; i < 4; ++i) {
                const int y0 = yb + dy - 1 + 2 * i;
                const bool ok = ((unsigned)y0 < 8u) & okx;
                const int s0 = ((y0 * 8 + x0) & 63) * 72 + kg8;
#pragma unroll
                for (int kci = 0; kci < 2; ++kci) {
                    v8bf b = ok ? *(const v8bf*)&tS[s0 + kci * 32] : vz;
                    acc[i] = __builtin_amdgcn_mfma_f32_16x16x32_bf16(
                        wh[dy * 3 + dx][kci], b, acc[i], 0, 0, 0);
                }
            }
        }
}

// Fused triple conv over the same tA (ah/Uz/Ur).
__device__ __forceinline__ void conv_mfma3(const __bf16* __restrict__ W0,
                                           const __bf16* __restrict__ W1,
                                           const __bf16* __restrict__ W2,
                                           const __bf16* tS,
                                           int l15, int kg8, int mt,
                                           v4f a0[4], v4f a1[4], v4f a2[4]) {
    v8bf vz;
#pragma unroll
    for (int q = 0; q < 8; ++q) vz[q] = (__bf16)0.f;
#pragma unroll
    for (int i = 0; i < 4; ++i) {
        a0[i] = (v4f){0.f, 0.f, 0.f, 0.f};
        a1[i] = (v4f){0.f, 0.f, 0.f, 0.f};
        a2[i] = (v4f){0.f, 0.f, 0.f, 0.f};
    }
    const int yb = l15 >> 3, xb = l15 & 7;
#pragma unroll
    for (int dy = 0; dy < 3; ++dy) {
        v8bf w0[3][2], w1[3][2], w2[3][2];
#pragma unroll
        for (int dx = 0; dx < 3; ++dx) {
            const int wrow = ((dy * 3 + dx) * 64 + mt * 16 + l15) * 64 + kg8;
#pragma unroll
            for (int kci = 0; kci < 2; ++kci) {
                w0[dx][kci] = *(const v8bf*)&W0[wrow + kci * 32];
                w1[dx][kci] = *(const v8bf*)&W1[wrow + kci * 32];
                w2[dx][kci] = *(const v8bf*)&W2[wrow + kci * 32];
            }
        }
#pragma unroll
        for (int dx = 0; dx < 3; ++dx) {
            const int x0 = xb + dx - 1;
            const bool okx = (unsigned)x0 < 8u;
#pragma unroll
            for (int i = 0; i < 4; ++i) {
                const int y0 = yb + dy - 1 + 2 * i;
                const bool ok = ((unsigned)y0 < 8u) & okx;
                const int s0 = ((y0 * 8 + x0) & 63) * 72 + kg8;
#pragma unroll
                for (int kci = 0; kci < 2; ++kci) {
                    v8bf b = ok ? *(const v8bf*)&tS[s0 + kci * 32] : vz;
                    a0[i] = __builtin_amdgcn_mfma_f32_16x16x32_bf16(w0[dx][kci], b, a0[i], 0, 0, 0);
                    a1[i] = __builtin_amdgcn_mfma_f32_16x16x32_bf16(w1[dx][kci], b, a1[i], 0, 0, 0);
                    a2[i] = __builtin_amdgcn_mfma_f32_16x16x32_bf16(w2[dx][kci], b, a2[i], 0, 0, 0);
                }
            }
        }
    }
}

// ---------------------------------------------------------------------------
// Whole recurrence in one kernel: grid 32 (one block per b), 256 threads.
// R8: 4 waves, 256-VGPR envelope. R9/R10: attv computed IN-BLOCK in a one-time
// preamble (T(wxpb[tp]) -> conv_mfma with att_x hi weights from WATTX ->
// fp16 attv_s), replacing the separate scalar-fp32 k_conv3x3 kernel.
__global__ __launch_bounds__(256) void k_recur(const float* __restrict__ att_b,
                                               const float* __restrict__ share_b,
                                               const float* __restrict__ fc1_w,
                                               const float* __restrict__ fc2_w,
                                               float* __restrict__ ws) {
    __shared__ float h_s[4096];                                   // h [k][s]
    __shared__ __attribute__((aligned(16))) __bf16 tA[64 * 72];   // T(in) [s][kp]
    __shared__ float cA[64 * 65];                                 // conv out / scratch
    __shared__ float cB[64 * 65];
    __shared__ float misc[1088];  // em|exs [0..511], ex|als [512..1023], h1|asum [1024..]
    __shared__ __attribute__((aligned(16))) _Float16 attv_s[32768];  // [tp][k][s] fp16
    const int b = blockIdx.x, tid = threadIdx.x;
    const int lane = tid & 63;
    const int wave = tid >> 6;            // 0..3
    const int mt = wave;
    const int l15 = lane & 15, kg = lane >> 4, kg8 = kg * 8;
    const __bf16* Wp = (const __bf16*)ws + WPB;
    const __bf16* Wattx = (const __bf16*)ws + WATTX_BF16;
    const float* wxpb = ws + WXPB_OFF;
    float* hsg = ws + HS_OFF;
    float* asg = ws + ASUM_OFF;

    for (int i = tid; i < 4096; i += 256) h_s[i] = 0.f;

    // ---- one-time preamble: attv[tp] = conv3x3(wxpb[b*8+tp], att_x) on MFMA
    for (int tp = 0; tp < 8; ++tp) {
        const float* src = wxpb + (b * 8 + tp) * 4096;
        for (int i = tid; i < 4096; i += 256) {
            int k = i >> 6, s = i & 63;          // coalesced global read
            tA[s * 72 + k] = (__bf16)src[i];
        }
        __syncthreads();
        v4f av[4];
        conv_mfma(Wattx, tA, l15, kg8, mt, av);
#pragma unroll
        for (int i2 = 0; i2 < 4; ++i2)
#pragma unroll
            for (int r = 0; r < 4; ++r)
                attv_s[tp * 4096 + (mt * 16 + kg * 4 + r) * 64 + i2 * 16 + l15] =
                    (_Float16)av[i2][r];
        __syncthreads();
    }

    float abvr[2];
#pragma unroll
    for (int rep = 0; rep < 2; ++rep) abvr[rep] = att_b[(tid + rep * 256) >> 3];
    float sb4[4];
#pragma unroll
    for (int r = 0; r < 4; ++r) sb4[r] = share_b[mt * 16 + kg * 4 + r];

    for (int t = 0; t < 8; ++t) {
        // ---- tA = T(h)
#pragma unroll
        for (int rep = 0; rep < 2; ++rep) {
            int s = tid & 63, g = (tid >> 6) + rep * 4;
#pragma unroll
            for (int q4 = 0; q4 < 2; ++q4) {
                v4bf hv;
#pragma unroll
                for (int q = 0; q < 4; ++q) hv[q] = (__bf16)h_s[(g * 8 + q4 * 4 + q) * 64 + s];
                *(v4bf*)&tA[s * 72 + g * 8 + q4 * 4] = hv;
            }
        }
        __syncthreads();
        // ---- fused ah/Uz/Ur convs: ah -> cA; az, ar stay in registers
        v4f az[4], ar[4];
        {
            v4f a[4];
            conv_mfma3(Wp, Wp + 2u * 73728u, Wp + 3u * 73728u, tA,
                       l15, kg8, mt, a, az, ar);
#pragma unroll
            for (int i = 0; i < 4; ++i)
#pragma unroll
                for (int r = 0; r < 4; ++r)
                    cA[(mt * 16 + kg * 4 + r) * 65 + i * 16 + l15] = a[i][r];
        }
        __syncthreads();
        // ---- e = relu(attv+ah); mean/max over s -> em/ex  (attv from LDS fp16)
#pragma unroll
        for (int rep = 0; rep < 2; ++rep) {
            int vt = tid + rep * 256;
            int kk = vt >> 3, yy = vt & 7;
            float ah8[8];
            const float* cr = &cA[kk * 65 + yy * 8];
#pragma unroll
            for (int xx = 0; xx < 8; ++xx) ah8[xx] = cr[xx] + abvr[rep];
            for (int tp = 0; tp < 8; ++tp) {
                v8h va = *(const v8h*)&attv_s[tp * 4096 + kk * 64 + yy * 8];
                float s_ = 0.f, m_ = 0.f;
#pragma unroll
                for (int xx = 0; xx < 8; ++xx) {
                    float v = fmaxf((float)va[xx] + ah8[xx], 0.f);
                    s_ += v;
                    m_ = fmaxf(m_, v);
                }
                s_ += __shfl_down(s_, 4, 8);
                s_ += __shfl_down(s_, 2, 8);
                s_ += __shfl_down(s_, 1, 8);
                m_ = fmaxf(m_, __shfl_down(m_, 4, 8));
                m_ = fmaxf(m_, __shfl_down(m_, 2, 8));
                m_ = fmaxf(m_, __shfl_down(m_, 1, 8));
                if (yy == 0) {
                    misc[tp * 64 + kk] = s_ * (1.f / 64.f);
                    misc[512 + tp * 64 + kk] = m_;
                }
            }
        }
        __syncthreads();
        // ---- fc1: 64 outputs x 4 partials (256 thr); 4-way acc split
        {
            int i2 = tid >> 2, part = tid & 3;
            int i = i2 & 31;
            const float* src = misc + ((i2 < 32) ? 0 : 512);
            const float* wrow = fc1_w + i * 512 + part * 128;
            const float* s2 = src + part * 128;
            float pa[4] = {0.f, 0.f, 0.f, 0.f};
#pragma unroll
            for (int c4 = 0; c4 < 32; ++c4) {
                float4 wv = *(const float4*)&wrow[c4 * 4];
                float4 sv = *(const float4*)&s2[c4 * 4];
                float* pp = &pa[c4 & 3];
                *pp = fmaf(wv.x, sv.x, *pp);
                *pp = fmaf(wv.y, sv.y, *pp);
                *pp = fmaf(wv.z, sv.z, *pp);
                *pp = fmaf(wv.w, sv.w, *pp);
            }
            float p = (pa[0] + pa[1]) + (pa[2] + pa[3]);
            p += __shfl_down(p, 2, 4);
            p += __shfl_down(p, 1, 4);
            if (part == 0) misc[1024 + i2] = fmaxf(p, 0.f);
        }
        __syncthreads();
        // ---- fc2 + tanh + exp -> exs at misc[0..511], float4 loads
#pragma unroll
        for (int rep = 0; rep < 2; ++rep) {
            int vt = tid + rep * 256;
            const float* w2 = fc2_w + vt * 32;
            float gm = 0.f, gx = 0.f;
#pragma unroll
            for (int i4 = 0; i4 < 8; ++i4) {
                float4 wv = *(const float4*)&w2[i4 * 4];
                gm = fmaf(wv.x, misc[1024 + i4 * 4 + 0], gm);
                gm = fmaf(wv.y, misc[1024 + i4 * 4 + 1], gm);
                gm = fmaf(wv.z, misc[1024 + i4 * 4 + 2], gm);
                gm = fmaf(wv.w, misc[1024 + i4 * 4 + 3], gm);
                gx = fmaf(wv.x, misc[1056 + i4 * 4 + 0], gx);
                gx = fmaf(wv.y, misc[1056 + i4 * 4 + 1], gx);
                gx = fmaf(wv.z, misc[1056 + i4 * 4 + 2], gx);
                gx = fmaf(wv.w, misc[1056 + i4 * 4 + 3], gx);
            }
            misc[vt] = expf(tanhf(gm + gx));
        }
        __syncthreads();
        // ---- softmax over T -> als at misc[512..1023]
#pragma unroll
        for (int rep = 0; rep < 2; ++rep) {
            int vt = tid + rep * 256;
            int k6 = vt & 63;
            float den = 0.f;
#pragma unroll
            for (int tp = 0; tp < 8; ++tp) den += misc[tp * 64 + k6];
            den += (den == 0.f) ? 1.f : 0.f;
            misc[512 + vt] = misc[vt] / den;
        }
        __syncthreads();
        // ---- wxtp: read wxpb from global (L2-resident), weighted by als;
        //      then tA = T(wxtp)
#pragma unroll
        for (int rep = 0; rep < 2; ++rep) {
            int vt = tid + rep * 256;
            int kk = vt >> 3, yy = vt & 7;
            float wx8[8];
#pragma unroll
            for (int xx = 0; xx < 8; ++xx) wx8[xx] = 0.f;
            const float* src0 = wxpb + b * 32768 + kk * 64 + yy * 8;
#pragma unroll
            for (int tp = 0; tp < 8; ++tp) {
                float al = misc[512 + tp * 64 + kk];
                float4 v0 = *(const float4*)&src0[tp * 4096];
                float4 v1 = *(const float4*)&src0[tp * 4096 + 4];
                float v[8] = {v0.x, v0.y, v0.z, v0.w, v1.x, v1.y, v1.z, v1.w};
#pragma unroll
                for (int xx = 0; xx < 8; ++xx) wx8[xx] = fmaf(al, v[xx], wx8[xx]);
            }
#pragma unroll
            for (int xx = 0; xx < 8; ++xx) tA[(yy * 8 + xx) * 72 + kk] = (__bf16)wx8[xx];
        }
        __syncthreads();
        // ---- share conv
        v4f ash[4];
        conv_mfma(Wp + 1u * 73728u, tA, l15, kg8, mt, ash);
        // ---- gates (frag domain); rh -> cB
        float zf[4][4], wof[4][4];
#pragma unroll
        for (int i = 0; i < 4; ++i)
#pragma unroll
            for (int r = 0; r < 4; ++r) {
                int ko = mt * 16 + kg * 4 + r;
                int s = i * 16 + l15;
                float wo = ash[i][r] + sb4[r];
                float z = 1.f / (1.f + expf(-(wo + az[i][r])));
                float rr = 1.f / (1.f + expf(-(wo + ar[i][r])));
                cB[ko * 65 + s] = rr * h_s[ko * 64 + s];
                zf[i][r] = z;
                wof[i][r] = wo;
            }
        __syncthreads();
        // ---- tA = T(rh)
#pragma unroll
        for (int rep = 0; rep < 2; ++rep) {
            int s = tid & 63, g = (tid >> 6) + rep * 4;
#pragma unroll
            for (int q4 = 0; q4 < 2; ++q4) {
                v4bf hv;
#pragma unroll
                for (int q = 0; q < 4; ++q) hv[q] = (__bf16)cB[(g * 8 + q4 * 4 + q) * 65 + s];
                *(v4bf*)&tA[s * 72 + g * 8 + q4 * 4] = hv;
            }
        }
        __syncthreads();
        // ---- Uh conv + final update (one wave per row: direct asum store)
        {
            v4f ach[4];
            conv_mfma(Wp + 4u * 73728u, tA, l15, kg8, mt, ach);
#pragma unroll
            for (int r = 0; r < 4; ++r) {
                int ko = mt * 16 + kg * 4 + r;
                float rsum = 0.f;
#pragma unroll
                for (int i = 0; i < 4; ++i) {
                    int s = i * 16 + l15;
                    float hh = tanhf(wof[i][r] + ach[i][r]);
                    float hold = h_s[ko * 64 + s];
                    float hn = (1.f - zf[i][r]) * hh + zf[i][r] * hold;
                    h_s[ko * 64 + s] = hn;
                    hsg[((t * 32 + b) * 64 + ko) * 64 + s] = hn;
                    rsum += hn;
                }
                rsum += __shfl_xor(rsum, 8, 16);
                rsum += __shfl_xor(rsum, 4, 16);
                rsum += __shfl_xor(rsum, 2, 16);
                rsum += __shfl_xor(rsum, 1, 16);
                if (l15 == 0) misc[1024 + ko] = rsum;
            }
        }
        __syncthreads();
        if (tid < 64) asg[b * 512 + t * 64 + tid] = misc[1024 + tid];
        __syncthreads();
    }
}

// ---------------------------------------------------------------------------
// VLAD: V[b,k,d] = sum_{t,hw} hs*xt - (sum_t asum)*centers. grid (8,32), 256 thr
__global__ __launch_bounds__(256) void k_vlad(const float* __restrict__ centers,
                                              const float* __restrict__ ws,
                                              float* __restrict__ out) {
    __shared__ float As[16 * 68];
    __shared__ float Bs[16 * 68];
    const int b = blockIdx.y;
    const int d0 = blockIdx.x * 64;
    const int tid = threadIdx.x;
    const int kq = tid & 15, dq = tid >> 4;
    const int lk = tid >> 2, q = tid & 3;
    const float* hs = ws + HS_OFF;
    const float* xt = ws + XT_OFF;
    float acc[4][4];
#pragma unroll
    for (int i = 0; i < 4; ++i)
#pragma unroll
        for (int j = 0; j < 4; ++j) acc[i][j] = 0.f;

    for (int rc = 0; rc < 512; rc += 16) {
        int t = rc >> 6, hw0 = rc & 63;
        float4 va = *(const float4*)&hs[((t * 32 + b) * 64 + lk) * 64 + hw0 + q * 4];
        float4 vb = *(const float4*)&xt[(b * 8 + t) * 32768 + (d0 + lk) * 64 + hw0 + q * 4];
        __syncthreads();
        As[(q * 4 + 0) * 68 + lk] = va.x;
        As[(q * 4 + 1) * 68 + lk] = va.y;
        As[(q * 4 + 2) * 68 + lk] = va.z;
        As[(q * 4 + 3) * 68 + lk] = va.w;
        Bs[(q * 4 + 0) * 68 + lk] = vb.x;
        Bs[(q * 4 + 1) * 68 + lk] = vb.y;
        Bs[(q * 4 + 2) * 68 + lk] = vb.z;
        Bs[(q * 4 + 3) * 68 + lk] = vb.w;
        __syncthreads();
#pragma unroll
        for (int cc = 0; cc < 16; ++cc) {
            float4 a = *(const float4*)&As[cc * 68 + kq * 4];
            float4 bb = *(const float4*)&Bs[cc * 68 + dq * 4];
            float av[4] = {a.x, a.y, a.z, a.w};
            float bv[4] = {bb.x, bb.y, bb.z, bb.w};
#pragma unroll
            for (int i = 0; i < 4; ++i)
#pragma unroll
                for (int j = 0; j < 4; ++j)
                    acc[i][j] = fmaf(av[i], bv[j], acc[i][j]);
        }
    }
    const float* asum = ws + ASUM_OFF;
#pragma unroll
    for (int i = 0; i < 4; ++i) {
        int k = kq * 4 + i;
        float at = 0.f;
#pragma unroll
        for (int tp = 0; tp < 8; ++tp) at += asum[b * 512 + tp * 64 + k];
        float4 cen = *(const float4*)&centers[k * 512 + d0 + dq * 4];
        float4 o = {acc[i][0] - at * cen.x, acc[i][1] - at * cen.y,
                    acc[i][2] - at * cen.z, acc[i][3] - at * cen.w};
        *(float4*)&out[b * 32768 + k * 512 + d0 + dq * 4] = o;
    }
}

// ---------------------------------------------------------------------------
__global__ __launch_bounds__(64) void k_norm1(float* __restrict__ out) {
    const int b = blockIdx.x >> 6, k = blockIdx.x & 63;
    float* p = out + b * 32768 + k * 512;
    const int tid = threadIdx.x;
    float v[8];
    float ss = 0.f;
#pragma unroll
    for (int i = 0; i < 8; ++i) {
        v[i] = p[tid + i * 64];
        ss = fmaf(v[i], v[i], ss);
    }
#pragma unroll
    for (int off = 32; off > 0; off >>= 1) ss += __shfl_down(ss, off, 64);
    ss = __shfl(ss, 0, 64);
    float sc = 1.f / fmaxf(sqrtf(ss), 1e-12f);
#pragma unroll
    for (int i = 0; i < 8; ++i) p[tid + i * 64] = v[i] * sc;
}

__global__ __launch_bounds__(256) void k_norm2(float* __restrict__ out) {
    __shared__ float red[4];
    __shared__ float stot;
    const int b = blockIdx.x;
    const int tid = threadIdx.x;
    float* p = out + b * 32768;
    float ss = 0.f;
    for (int i = 0; i < 32; ++i) {
        float4 v = *(const float4*)&p[tid * 4 + i * 1024];
        ss += v.x * v.x + v.y * v.y + v.z * v.z + v.w * v.w;
    }
#pragma unroll
    for (int off = 32; off > 0; off >>= 1) ss += __shfl_down(ss, off, 64);
    if ((tid & 63) == 0) red[tid >> 6] = ss;
    __syncthreads();
    if (tid == 0) stot = 1.f / fmaxf(sqrtf(red[0] + red[1] + red[2] + red[3]), 1e-12f);
    __syncthreads();
    float sc = stot;
    for (int i = 0; i < 32; ++i) {
        float4 v = *(const float4*)&p[tid * 4 + i * 1024];
        v.x *= sc; v.y *= sc; v.z *= sc; v.w *= sc;
        *(float4*)&p[tid * 4 + i * 1024] = v;
    }
}

// ---------------------------------------------------------------------------
extern "C" void kernel_launch(void* const* d_in, const int* in_sizes, int n_in,
                              void* d_out, int out_size, void* d_ws, size_t ws_size,
                              hipStream_t stream) {
    const float* x       = (const float*)d_in[0];
    const float* redu_w  = (const float*)d_in[1];
    const float* redu_b  = (const float*)d_in[2];
    const float* w_x     = (const float*)d_in[3];
    const float* att_x   = (const float*)d_in[4];
    const float* att_h_w = (const float*)d_in[5];
    const float* att_b   = (const float*)d_in[6];
    const float* share_w = (const float*)d_in[7];
    const float* share_b = (const float*)d_in[8];
    const float* U_r     = (const float*)d_in[9];
    const float* U_z     = (const float*)d_in[10];
    const float* U_h     = (const float*)d_in[11];
    const float* centers = (const float*)d_in[12];
    const float* fc1_w   = (const float*)d_in[13];
    const float* fc2_w   = (const float*)d_in[14];
    float* ws = (float*)d_ws;
    float* out = (float*)d_out;

    k_prep<<<dim3(3200), dim3(256), 0, stream>>>(redu_w, w_x, ws);
    k_prep_w<<<dim3(864), dim3(256), 0, stream>>>(att_h_w, share_w, U_z, U_r, U_h,
                                                  att_x, ws);
    k_gemm_xt_mfma<<<dim3(2, 256), dim3(256), 0, stream>>>(x, redu_b, ws);
    k_gemm_wxpb<<<dim3(256), dim3(256), 0, stream>>>(ws);
    k_recur<<<dim3(32), dim3(256), 0, stream>>>(att_b, share_b, fc1_w, fc2_w, ws);
    k_vlad<<<dim3(8, 32), dim3(256), 0, stream>>>(centers, ws, out);
    k_norm1<<<dim3(2048), dim3(64), 0, stream>>>(out);
    k_norm2<<<dim3(32), dim3(256), 0, stream>>>(out);
}